// Round 1
// baseline (125.500 us; speedup 1.0000x reference)
//
#include <hip/hip_runtime.h>

#define B_ 2
#define N_ 2048
#define DIM_ 1024
#define H_ 8
#define DH_ 64
#define DI_ 512
#define WIN_ 512
#define NCPAD 1664  // 13*128 padded proj cols: 512 q | 1024 kv | 8 g | 8 mix | 112 pad

typedef __bf16 bf16x8 __attribute__((ext_vector_type(8)));
typedef unsigned short ushortx8 __attribute__((ext_vector_type(8)));
typedef float floatx4 __attribute__((ext_vector_type(4)));

__device__ inline unsigned short f2bf(float f) {
  union { float f; unsigned u; } v; v.f = f;
  unsigned r = v.u + 0x7FFFu + ((v.u >> 16) & 1u);
  return (unsigned short)(r >> 16);
}
__device__ inline float sigmoidf_(float x) { return 1.0f / (1.0f + __expf(-x)); }

// ---------------- prep kernels ----------------
__global__ void k_tokens_bf16(const float* __restrict__ t, unsigned short* __restrict__ o, int n4) {
  int i = blockIdx.x * blockDim.x + threadIdx.x;
  if (i >= n4) return;
  float4 v = reinterpret_cast<const float4*>(t)[i];
  ushort4 r;
  r.x = f2bf(v.x); r.y = f2bf(v.y); r.z = f2bf(v.z); r.w = f2bf(v.w);
  reinterpret_cast<ushort4*>(o)[i] = r;
}

__global__ void k_wcat(const float* __restrict__ Wq, const float* __restrict__ Wkv,
                       const float* __restrict__ Wg, const float* __restrict__ Wmix,
                       unsigned short* __restrict__ Wcat) {
  int idx = blockIdx.x * blockDim.x + threadIdx.x;
  if (idx >= NCPAD * DIM_) return;
  int r = idx >> 10;        // output col (row of Wcat^T)
  int c = idx & (DIM_ - 1); // input dim
  float v;
  if (r < 512)       v = Wq[c * 512 + r];
  else if (r < 1536) v = Wkv[c * 1024 + (r - 512)];
  else if (r < 1544) v = Wg[c * 8 + (r - 1536)];
  else if (r < 1552) v = Wmix[c * 8 + (r - 1544)];
  else               v = 0.0f;
  Wcat[idx] = f2bf(v);
}

__global__ void k_wo(const float* __restrict__ Wo, unsigned short* __restrict__ Wot) {
  int idx = blockIdx.x * blockDim.x + threadIdx.x;
  if (idx >= DIM_ * DI_) return;
  int r = idx >> 9;        // output col of final gemm
  int c = idx & (DI_ - 1); // k dim
  Wot[idx] = f2bf(Wo[c * DIM_ + r]);
}

// ---------------- 128x128 MFMA GEMM, C = A(bf16 [M][K]) * Bt(bf16 [N][K])^T -> fp32 [M][N]
__global__ __launch_bounds__(256) void k_gemm_bt(const unsigned short* __restrict__ A,
                                                 const unsigned short* __restrict__ Bt,
                                                 float* __restrict__ C,
                                                 int M, int Nc, int K) {
  __shared__ __align__(16) unsigned short As[128 * 32];
  __shared__ __align__(16) unsigned short Bs[128 * 32];
  const int tid = threadIdx.x;
  const int lane = tid & 63;
  const int wid = tid >> 6;
  const int m0 = blockIdx.y * 128;
  const int n0 = blockIdx.x * 128;
  const int wr = (wid >> 1) * 64;
  const int wc = (wid & 1) * 64;
  const int srow = tid >> 2;        // 0..63
  const int scol = (tid & 3) << 3;  // 0,8,16,24
  const int lr = lane & 15;
  const int lk = (lane >> 4) << 3;
  floatx4 acc[4][4] = {};
  const unsigned short* ap0 = A + (size_t)(m0 + srow) * K + scol;
  const unsigned short* ap1 = ap0 + (size_t)64 * K;
  const unsigned short* bp0 = Bt + (size_t)(n0 + srow) * K + scol;
  const unsigned short* bp1 = bp0 + (size_t)64 * K;
  for (int k0 = 0; k0 < K; k0 += 32) {
    ushortx8 av0 = *reinterpret_cast<const ushortx8*>(ap0 + k0);
    ushortx8 av1 = *reinterpret_cast<const ushortx8*>(ap1 + k0);
    ushortx8 bv0 = *reinterpret_cast<const ushortx8*>(bp0 + k0);
    ushortx8 bv1 = *reinterpret_cast<const ushortx8*>(bp1 + k0);
    __syncthreads();
    *reinterpret_cast<ushortx8*>(&As[srow * 32 + scol]) = av0;
    *reinterpret_cast<ushortx8*>(&As[(srow + 64) * 32 + scol]) = av1;
    *reinterpret_cast<ushortx8*>(&Bs[srow * 32 + scol]) = bv0;
    *reinterpret_cast<ushortx8*>(&Bs[(srow + 64) * 32 + scol]) = bv1;
    __syncthreads();
    bf16x8 af[4], bfr[4];
#pragma unroll
    for (int i = 0; i < 4; ++i)
      af[i] = *reinterpret_cast<const bf16x8*>(&As[(wr + i * 16 + lr) * 32 + lk]);
#pragma unroll
    for (int j = 0; j < 4; ++j)
      bfr[j] = *reinterpret_cast<const bf16x8*>(&Bs[(wc + j * 16 + lr) * 32 + lk]);
#pragma unroll
    for (int i = 0; i < 4; ++i)
#pragma unroll
      for (int j = 0; j < 4; ++j)
        acc[i][j] = __builtin_amdgcn_mfma_f32_16x16x32_bf16(af[i], bfr[j], acc[i][j], 0, 0, 0);
  }
  const int r0 = (lane >> 4) << 2;
#pragma unroll
  for (int i = 0; i < 4; ++i)
#pragma unroll
    for (int j = 0; j < 4; ++j) {
      float* cp = C + (size_t)(m0 + wr + i * 16 + r0) * Nc + n0 + wc + j * 16 + lr;
#pragma unroll
      for (int r = 0; r < 4; ++r) cp[(size_t)r * Nc] = acc[i][j][r];
    }
}

// ---------------- post-projection: RoPE, scale, value-residual lerp, gates ----------------
__global__ __launch_bounds__(256) void k_post(const float* __restrict__ proj,
                                              const float* __restrict__ vres,
                                              unsigned short* __restrict__ Qb,
                                              unsigned short* __restrict__ Kb,
                                              unsigned short* __restrict__ Vt,
                                              float* __restrict__ gates) {
  const int row = blockIdx.x;  // b*N + n
  const int t = threadIdx.x;
  const int b = row >> 11;
  const int n = row & (N_ - 1);
  const float* pr = proj + (size_t)row * NCPAD;
  if (t < H_) gates[(size_t)(b * H_ + t) * N_ + n] = sigmoidf_(pr[1536 + t]);
  const int h = t >> 5;
  const int t2 = t & 31;
  // angle = n * 10000^(-t2/32)
  float ang = (float)n * __expf(-(float)t2 * (9.210340371976184f / 32.0f));
  float sv, cv;
  sincosf(ang, &sv, &cv);
  const size_t base = ((size_t)(b * H_ + h) * N_ + n) * DH_ + 2 * t2;
  float x0 = pr[h * 64 + 2 * t2], x1 = pr[h * 64 + 2 * t2 + 1];
  Qb[base]     = f2bf((x0 * cv - x1 * sv) * 0.125f);
  Qb[base + 1] = f2bf((x1 * cv + x0 * sv) * 0.125f);
  x0 = pr[512 + h * 64 + 2 * t2]; x1 = pr[512 + h * 64 + 2 * t2 + 1];
  Kb[base]     = f2bf(x0 * cv - x1 * sv);
  Kb[base + 1] = f2bf(x1 * cv + x0 * sv);
  const float mix = sigmoidf_(pr[1544 + h]);
#pragma unroll
  for (int e = 0; e < 2; ++e) {
    int d = 2 * t2 + e;
    float v = pr[1024 + h * 64 + d];
    float res = vres[((size_t)(b * H_ + h) * N_ + n) * DH_ + d];
    v = v + (res - v) * mix;
    Vt[((size_t)(b * H_ + h) * DH_ + d) * N_ + n] = f2bf(v);  // transposed [b,h,d,n]
  }
}

// ---------------- windowed flash attention: 1 wave per 16 queries ----------------
__global__ __launch_bounds__(64) void k_attn(const unsigned short* __restrict__ Qb,
                                             const unsigned short* __restrict__ Kb,
                                             const unsigned short* __restrict__ Vt,
                                             const float* __restrict__ gates,
                                             unsigned short* __restrict__ Og) {
  __shared__ __align__(16) unsigned short Plds[16 * 32];
  const int blk = blockIdx.x;
  const int bh = blk >> 7;  // N_/16 = 128 q-blocks per (b,h)
  const int qb = blk & 127;
  const int b = bh >> 3, h = bh & 7;
  const int qi0 = qb * 16;
  const int lane = threadIdx.x;
  const int lr = lane & 15;
  const int lk = (lane >> 4) << 3;
  const unsigned short* Qh = Qb + (size_t)bh * N_ * DH_;
  const unsigned short* Kh = Kb + (size_t)bh * N_ * DH_;
  const unsigned short* Vh = Vt + (size_t)bh * DH_ * N_;
  bf16x8 aq0 = *reinterpret_cast<const bf16x8*>(Qh + (qi0 + lr) * DH_ + lk);
  bf16x8 aq1 = *reinterpret_cast<const bf16x8*>(Qh + (qi0 + lr) * DH_ + 32 + lk);
  floatx4 o[4] = {};
  float m[4] = {-1e30f, -1e30f, -1e30f, -1e30f};
  float l[4] = {0.f, 0.f, 0.f, 0.f};
  int jlo = qi0 - WIN_;
  if (jlo < 0) jlo = 0;
  jlo &= ~31;
  for (int j0 = jlo; j0 <= qi0 + 15; j0 += 32) {
    bf16x8 k00 = *reinterpret_cast<const bf16x8*>(Kh + (j0 + lr) * DH_ + lk);
    bf16x8 k01 = *reinterpret_cast<const bf16x8*>(Kh + (j0 + lr) * DH_ + 32 + lk);
    bf16x8 k10 = *reinterpret_cast<const bf16x8*>(Kh + (j0 + 16 + lr) * DH_ + lk);
    bf16x8 k11 = *reinterpret_cast<const bf16x8*>(Kh + (j0 + 16 + lr) * DH_ + 32 + lk);
    floatx4 c0 = {}, c1 = {};
    c0 = __builtin_amdgcn_mfma_f32_16x16x32_bf16(aq0, k00, c0, 0, 0, 0);
    c0 = __builtin_amdgcn_mfma_f32_16x16x32_bf16(aq1, k01, c0, 0, 0, 0);
    c1 = __builtin_amdgcn_mfma_f32_16x16x32_bf16(aq0, k10, c1, 0, 0, 0);
    c1 = __builtin_amdgcn_mfma_f32_16x16x32_bf16(aq1, k11, c1, 0, 0, 0);
#pragma unroll
    for (int r = 0; r < 4; ++r) {
      const int i = qi0 + ((lane >> 4) << 2) + r;
      float s0 = c0[r], s1 = c1[r];
      const int j_0 = j0 + lr, j_1 = j0 + 16 + lr;
      const int d0 = i - j_0, d1 = i - j_1;
      if (d0 < 0 || d0 > WIN_) s0 = -1e30f;
      if (d1 < 0 || d1 > WIN_) s1 = -1e30f;
      float mx = fmaxf(s0, s1);
#pragma unroll
      for (int off = 1; off < 16; off <<= 1) mx = fmaxf(mx, __shfl_xor(mx, off, 16));
      const float mnew = fmaxf(m[r], mx);
      const float sc = __expf(m[r] - mnew);
      const float p0 = __expf(s0 - mnew);
      const float p1 = __expf(s1 - mnew);
      float ps = p0 + p1;
#pragma unroll
      for (int off = 1; off < 16; off <<= 1) ps += __shfl_xor(ps, off, 16);
      l[r] = l[r] * sc + ps;
      m[r] = mnew;
      o[0][r] *= sc; o[1][r] *= sc; o[2][r] *= sc; o[3][r] *= sc;
      const int prow = ((lane >> 4) << 2) + r;
      Plds[prow * 32 + lr] = f2bf(p0);
      Plds[prow * 32 + 16 + lr] = f2bf(p1);
    }
    __syncthreads();
    bf16x8 pa = *reinterpret_cast<const bf16x8*>(&Plds[lr * 32 + lk]);
#pragma unroll
    for (int nb = 0; nb < 4; ++nb) {
      bf16x8 bv = *reinterpret_cast<const bf16x8*>(Vh + (size_t)(nb * 16 + lr) * N_ + j0 + lk);
      o[nb] = __builtin_amdgcn_mfma_f32_16x16x32_bf16(pa, bv, o[nb], 0, 0, 0);
    }
    __syncthreads();
  }
#pragma unroll
  for (int r = 0; r < 4; ++r) {
    const int i = qi0 + ((lane >> 4) << 2) + r;
    const float g = gates[(size_t)bh * N_ + i] / l[r];
#pragma unroll
    for (int nb = 0; nb < 4; ++nb)
      Og[((size_t)(b * N_ + i)) * DI_ + h * DH_ + nb * 16 + lr] = f2bf(o[nb][r] * g);
  }
}

extern "C" void kernel_launch(void* const* d_in, const int* in_sizes, int n_in,
                              void* d_out, int out_size, void* d_ws, size_t ws_size,
                              hipStream_t stream) {
  const float* tokens = (const float*)d_in[0];
  const float* vres   = (const float*)d_in[1];
  const float* Wq     = (const float*)d_in[2];
  const float* Wkv    = (const float*)d_in[3];
  const float* Wo     = (const float*)d_in[4];
  const float* Wg     = (const float*)d_in[5];
  const float* Wmix   = (const float*)d_in[6];
  float* out = (float*)d_out;
  char* ws = (char*)d_ws;
  // workspace layout (bytes)
  unsigned short* tokb = (unsigned short*)(ws);              // 4096*1024*2  = 8388608
  unsigned short* wcat = (unsigned short*)(ws + 8388608);    // 1664*1024*2  = 3407872
  unsigned short* wot  = (unsigned short*)(ws + 11796480);   // 1024*512*2   = 1048576
  float*          proj = (float*)(ws + 12845056);            // 4096*1664*4  = 27262976
  unsigned short* Qb   = (unsigned short*)(ws + 40108032);   // 4194304
  unsigned short* Kb   = (unsigned short*)(ws + 44302336);   // 4194304
  unsigned short* Vt   = (unsigned short*)(ws + 48496640);   // 4194304
  float*          gates= (float*)(ws + 52690944);            // 131072
  unsigned short* Og   = (unsigned short*)(ws + 52822016);   // 4194304
  (void)in_sizes; (void)n_in; (void)out_size; (void)ws_size;

  k_tokens_bf16<<<4096, 256, 0, stream>>>(tokens, tokb, (B_ * N_ * DIM_) / 4);
  k_wcat<<<6656, 256, 0, stream>>>(Wq, Wkv, Wg, Wmix, wcat);
  k_wo<<<2048, 256, 0, stream>>>(Wo, wot);

  dim3 g1(NCPAD / 128, (B_ * N_) / 128);
  k_gemm_bt<<<g1, 256, 0, stream>>>(tokb, wcat, proj, B_ * N_, NCPAD, DIM_);

  k_post<<<B_ * N_, 256, 0, stream>>>(proj, vres, Qb, Kb, Vt, gates);

  k_attn<<<B_ * H_ * (N_ / 16), 64, 0, stream>>>(Qb, Kb, Vt, gates, Og);

  dim3 g2(DIM_ / 128, (B_ * N_) / 128);
  k_gemm_bt<<<g2, 256, 0, stream>>>(Og, wot, out, B_ * N_, DIM_, DI_);
}

// Round 2
// 116.607 us; speedup vs baseline: 1.0763x; 1.0763x over previous
//
#include <hip/hip_runtime.h>

#define B_ 2
#define N_ 2048
#define DIM_ 1024
#define H_ 8
#define DH_ 64
#define DI_ 512
#define WIN_ 512
#define NCPAD 1664  // 13*128 padded proj cols: 512 q | 1024 kv | 8 g | 8 mix | 112 pad

typedef __bf16 bf16x8 __attribute__((ext_vector_type(8)));
typedef unsigned short ushortx8 __attribute__((ext_vector_type(8)));
typedef float floatx4 __attribute__((ext_vector_type(4)));

__device__ inline unsigned short f2bf(float f) {
  union { float f; unsigned u; } v; v.f = f;
  unsigned r = v.u + 0x7FFFu + ((v.u >> 16) & 1u);
  return (unsigned short)(r >> 16);
}
__device__ inline float sigmoidf_(float x) { return 1.0f / (1.0f + __expf(-x)); }

__device__ __forceinline__ void gload_lds16(const unsigned short* g, unsigned short* l) {
  __builtin_amdgcn_global_load_lds(
      (const __attribute__((address_space(1))) void*)g,
      (__attribute__((address_space(3))) void*)l,
      16, 0, 0);
}

// ---------------- prep: tokens fp32 -> bf16 ----------------
__global__ void k_tokens_bf16(const float* __restrict__ t, unsigned short* __restrict__ o, int n4) {
  int i = blockIdx.x * blockDim.x + threadIdx.x;
  if (i >= n4) return;
  float4 v = reinterpret_cast<const float4*>(t)[i];
  ushort4 r;
  r.x = f2bf(v.x); r.y = f2bf(v.y); r.z = f2bf(v.z); r.w = f2bf(v.w);
  reinterpret_cast<ushort4*>(o)[i] = r;
}

// ---------------- prep: coalesced LDS-tiled transposes of Wq/Wkv/Wo + Wg/Wmix strip ----------------
__global__ __launch_bounds__(256) void k_wprep(const float* __restrict__ Wq,
                                               const float* __restrict__ Wkv,
                                               const float* __restrict__ Wo,
                                               const float* __restrict__ Wg,
                                               const float* __restrict__ Wmix,
                                               unsigned short* __restrict__ wcat,
                                               unsigned short* __restrict__ wot) {
  const int z = blockIdx.z;
  const int tx = threadIdx.x, ty = threadIdx.y;
  if (z == 3) {
    // Wg/Wmix -> wcat rows 1536..1551
    int flat = blockIdx.y * gridDim.x + blockIdx.x;
    if (flat >= 64) return;
    int idx = flat * 256 + ty * 32 + tx;      // 0..16383
    int j = idx >> 10;                        // 0..15
    int c = idx & 1023;
    float v = (j < 8) ? Wg[c * 8 + j] : Wmix[c * 8 + (j - 8)];
    wcat[(size_t)(1536 + j) * 1024 + c] = f2bf(v);
    return;
  }
  const float* in;
  unsigned short* out;
  int Rin, Cin;
  if (z == 0)      { in = Wq;  out = wcat;              Rin = 1024; Cin = 512; }
  else if (z == 1) { in = Wkv; out = wcat + 512 * 1024; Rin = 1024; Cin = 1024; }
  else             { in = Wo;  out = wot;               Rin = 512;  Cin = 1024; }
  const int c0 = blockIdx.x * 32, r0 = blockIdx.y * 32;
  if (c0 >= Cin || r0 >= Rin) return;
  __shared__ float t[32][33];
#pragma unroll
  for (int i = 0; i < 4; ++i)
    t[ty + i * 8][tx] = in[(size_t)(r0 + ty + i * 8) * Cin + c0 + tx];
  __syncthreads();
#pragma unroll
  for (int i = 0; i < 4; ++i)
    out[(size_t)(c0 + ty + i * 8) * Rin + r0 + tx] = f2bf(t[tx][ty + i * 8]);
}

// ---------------- m97-structure GEMM: C = A(bf16 [M][K]) * Bt(bf16 [Nc][K])^T -> fp32 [M][Nc]
__global__ __launch_bounds__(256) void k_gemm97(const unsigned short* __restrict__ A,
                                                const unsigned short* __restrict__ Bt,
                                                float* __restrict__ C,
                                                int M, int Nc, int K) {
  __shared__ __align__(16) unsigned short As[128 * 32];
  __shared__ __align__(16) unsigned short Bs[128 * 32];
  const int tid = threadIdx.x;
  const int lane = tid & 63;
  const int wid = tid >> 6;
  const int m0 = blockIdx.y * 128;
  const int n0 = blockIdx.x * 128;
  const int wr = (wid >> 1) * 64;
  const int wc = (wid & 1) * 64;
  const int lr = lane & 15;
  const int lk = (lane >> 4) << 3;
  const int srow = tid >> 2;        // 0..63
  const int scol = (tid & 3) << 3;  // 0,8,16,24
  const unsigned short* a0 = A + (size_t)(m0 + srow) * K + scol;
  const unsigned short* a1 = A + (size_t)(m0 + 64 + srow) * K + scol;
  const unsigned short* b0 = Bt + (size_t)(n0 + srow) * K + scol;
  const unsigned short* b1 = Bt + (size_t)(n0 + 64 + srow) * K + scol;
  unsigned short* lA0 = (unsigned short*)((char*)As + wid * 1024);
  unsigned short* lA1 = (unsigned short*)((char*)As + 4096 + wid * 1024);
  unsigned short* lB0 = (unsigned short*)((char*)Bs + wid * 1024);
  unsigned short* lB1 = (unsigned short*)((char*)Bs + 4096 + wid * 1024);
  floatx4 acc[4][4] = {};
  for (int k0 = 0; k0 < K; k0 += 32) {
    __syncthreads();
    gload_lds16(a0 + k0, lA0);
    gload_lds16(a1 + k0, lA1);
    gload_lds16(b0 + k0, lB0);
    gload_lds16(b1 + k0, lB1);
    __syncthreads();
    bf16x8 af[4], bfr[4];
#pragma unroll
    for (int i = 0; i < 4; ++i)
      af[i] = *reinterpret_cast<const bf16x8*>(&As[(wr + i * 16 + lr) * 32 + lk]);
#pragma unroll
    for (int j = 0; j < 4; ++j)
      bfr[j] = *reinterpret_cast<const bf16x8*>(&Bs[(wc + j * 16 + lr) * 32 + lk]);
#pragma unroll
    for (int i = 0; i < 4; ++i)
#pragma unroll
      for (int j = 0; j < 4; ++j)
        acc[i][j] = __builtin_amdgcn_mfma_f32_16x16x32_bf16(af[i], bfr[j], acc[i][j], 0, 0, 0);
  }
  const int r0 = (lane >> 4) << 2;
#pragma unroll
  for (int i = 0; i < 4; ++i)
#pragma unroll
    for (int j = 0; j < 4; ++j) {
      float* cp = C + (size_t)(m0 + wr + i * 16 + r0) * Nc + n0 + wc + j * 16 + lr;
#pragma unroll
      for (int r = 0; r < 4; ++r) cp[(size_t)r * Nc] = acc[i][j][r];
    }
}

// ---------------- post-projection: RoPE, scale, value-residual lerp, gates ----------------
__global__ __launch_bounds__(256) void k_post(const float* __restrict__ proj,
                                              const float* __restrict__ vres,
                                              unsigned short* __restrict__ Qb,
                                              unsigned short* __restrict__ Kb,
                                              unsigned short* __restrict__ Vt,
                                              float* __restrict__ gates) {
  const int row = blockIdx.x;  // b*N + n
  const int t = threadIdx.x;
  const int b = row >> 11;
  const int n = row & (N_ - 1);
  const float* pr = proj + (size_t)row * NCPAD;
  if (t < H_) gates[(size_t)(b * H_ + t) * N_ + n] = sigmoidf_(pr[1536 + t]);
  const int h = t >> 5;
  const int t2 = t & 31;
  float ang = (float)n * __expf(-(float)t2 * (9.210340371976184f / 32.0f));
  float sv, cv;
  sincosf(ang, &sv, &cv);
  const size_t base = ((size_t)(b * H_ + h) * N_ + n) * DH_ + 2 * t2;
  float x0 = pr[h * 64 + 2 * t2], x1 = pr[h * 64 + 2 * t2 + 1];
  Qb[base]     = f2bf((x0 * cv - x1 * sv) * 0.125f);
  Qb[base + 1] = f2bf((x1 * cv + x0 * sv) * 0.125f);
  x0 = pr[512 + h * 64 + 2 * t2]; x1 = pr[512 + h * 64 + 2 * t2 + 1];
  Kb[base]     = f2bf(x0 * cv - x1 * sv);
  Kb[base + 1] = f2bf(x1 * cv + x0 * sv);
  const float mix = sigmoidf_(pr[1544 + h]);
#pragma unroll
  for (int e = 0; e < 2; ++e) {
    int d = 2 * t2 + e;
    float v = pr[1024 + h * 64 + d];
    float res = vres[((size_t)(b * H_ + h) * N_ + n) * DH_ + d];
    v = v + (res - v) * mix;
    Vt[((size_t)(b * H_ + h) * DH_ + d) * N_ + n] = f2bf(v);  // transposed [b,h,d,n]
  }
}

// ---------------- windowed flash attention: 1 wave per 16 queries ----------------
__global__ __launch_bounds__(64) void k_attn(const unsigned short* __restrict__ Qb,
                                             const unsigned short* __restrict__ Kb,
                                             const unsigned short* __restrict__ Vt,
                                             const float* __restrict__ gates,
                                             unsigned short* __restrict__ Og) {
  __shared__ __align__(16) unsigned short Plds[16 * 32];
  const int blk = blockIdx.x;
  const int bh = blk >> 7;  // N_/16 = 128 q-blocks per (b,h)
  const int qb = blk & 127;
  const int b = bh >> 3, h = bh & 7;
  const int qi0 = qb * 16;
  const int lane = threadIdx.x;
  const int lr = lane & 15;
  const int lk = (lane >> 4) << 3;
  const unsigned short* Qh = Qb + (size_t)bh * N_ * DH_;
  const unsigned short* Kh = Kb + (size_t)bh * N_ * DH_;
  const unsigned short* Vh = Vt + (size_t)bh * DH_ * N_;
  bf16x8 aq0 = *reinterpret_cast<const bf16x8*>(Qh + (qi0 + lr) * DH_ + lk);
  bf16x8 aq1 = *reinterpret_cast<const bf16x8*>(Qh + (qi0 + lr) * DH_ + 32 + lk);
  floatx4 o[4] = {};
  float m[4] = {-1e30f, -1e30f, -1e30f, -1e30f};
  float l[4] = {0.f, 0.f, 0.f, 0.f};
  int jlo = qi0 - WIN_;
  if (jlo < 0) jlo = 0;
  jlo &= ~31;
  for (int j0 = jlo; j0 <= qi0 + 15; j0 += 32) {
    bf16x8 k00 = *reinterpret_cast<const bf16x8*>(Kh + (j0 + lr) * DH_ + lk);
    bf16x8 k01 = *reinterpret_cast<const bf16x8*>(Kh + (j0 + lr) * DH_ + 32 + lk);
    bf16x8 k10 = *reinterpret_cast<const bf16x8*>(Kh + (j0 + 16 + lr) * DH_ + lk);
    bf16x8 k11 = *reinterpret_cast<const bf16x8*>(Kh + (j0 + 16 + lr) * DH_ + 32 + lk);
    floatx4 c0 = {}, c1 = {};
    c0 = __builtin_amdgcn_mfma_f32_16x16x32_bf16(aq0, k00, c0, 0, 0, 0);
    c0 = __builtin_amdgcn_mfma_f32_16x16x32_bf16(aq1, k01, c0, 0, 0, 0);
    c1 = __builtin_amdgcn_mfma_f32_16x16x32_bf16(aq0, k10, c1, 0, 0, 0);
    c1 = __builtin_amdgcn_mfma_f32_16x16x32_bf16(aq1, k11, c1, 0, 0, 0);
#pragma unroll
    for (int r = 0; r < 4; ++r) {
      const int i = qi0 + ((lane >> 4) << 2) + r;
      float s0 = c0[r], s1 = c1[r];
      const int j_0 = j0 + lr, j_1 = j0 + 16 + lr;
      const int d0 = i - j_0, d1 = i - j_1;
      if (d0 < 0 || d0 > WIN_) s0 = -1e30f;
      if (d1 < 0 || d1 > WIN_) s1 = -1e30f;
      float mx = fmaxf(s0, s1);
#pragma unroll
      for (int off = 1; off < 16; off <<= 1) mx = fmaxf(mx, __shfl_xor(mx, off, 16));
      const float mnew = fmaxf(m[r], mx);
      const float sc = __expf(m[r] - mnew);
      const float p0 = __expf(s0 - mnew);
      const float p1 = __expf(s1 - mnew);
      float ps = p0 + p1;
#pragma unroll
      for (int off = 1; off < 16; off <<= 1) ps += __shfl_xor(ps, off, 16);
      l[r] = l[r] * sc + ps;
      m[r] = mnew;
      o[0][r] *= sc; o[1][r] *= sc; o[2][r] *= sc; o[3][r] *= sc;
      const int prow = ((lane >> 4) << 2) + r;
      Plds[prow * 32 + lr] = f2bf(p0);
      Plds[prow * 32 + 16 + lr] = f2bf(p1);
    }
    __syncthreads();
    bf16x8 pa = *reinterpret_cast<const bf16x8*>(&Plds[lr * 32 + lk]);
#pragma unroll
    for (int nb = 0; nb < 4; ++nb) {
      bf16x8 bv = *reinterpret_cast<const bf16x8*>(Vh + (size_t)(nb * 16 + lr) * N_ + j0 + lk);
      o[nb] = __builtin_amdgcn_mfma_f32_16x16x32_bf16(pa, bv, o[nb], 0, 0, 0);
    }
    __syncthreads();
  }
#pragma unroll
  for (int r = 0; r < 4; ++r) {
    const int i = qi0 + ((lane >> 4) << 2) + r;
    const float g = gates[(size_t)bh * N_ + i] / l[r];
#pragma unroll
    for (int nb = 0; nb < 4; ++nb)
      Og[((size_t)(b * N_ + i)) * DI_ + h * DH_ + nb * 16 + lr] = f2bf(o[nb][r] * g);
  }
}

extern "C" void kernel_launch(void* const* d_in, const int* in_sizes, int n_in,
                              void* d_out, int out_size, void* d_ws, size_t ws_size,
                              hipStream_t stream) {
  const float* tokens = (const float*)d_in[0];
  const float* vres   = (const float*)d_in[1];
  const float* Wq     = (const float*)d_in[2];
  const float* Wkv    = (const float*)d_in[3];
  const float* Wo     = (const float*)d_in[4];
  const float* Wg     = (const float*)d_in[5];
  const float* Wmix   = (const float*)d_in[6];
  float* out = (float*)d_out;
  char* ws = (char*)d_ws;
  unsigned short* tokb = (unsigned short*)(ws);              // 4096*1024*2  = 8388608
  unsigned short* wcat = (unsigned short*)(ws + 8388608);    // 1664*1024*2  = 3407872
  unsigned short* wot  = (unsigned short*)(ws + 11796480);   // 1024*512*2   = 1048576
  float*          proj = (float*)(ws + 12845056);            // 4096*1664*4  = 27262976
  unsigned short* Qb   = (unsigned short*)(ws + 40108032);   // 4194304
  unsigned short* Kb   = (unsigned short*)(ws + 44302336);   // 4194304
  unsigned short* Vt   = (unsigned short*)(ws + 48496640);   // 4194304
  float*          gates= (float*)(ws + 52690944);            // 131072
  unsigned short* Og   = (unsigned short*)(ws + 52822016);   // 4194304
  (void)in_sizes; (void)n_in; (void)out_size; (void)ws_size;

  k_tokens_bf16<<<4096, 256, 0, stream>>>(tokens, tokb, (B_ * N_ * DIM_) / 4);

  dim3 wpgrid(32, 32, 4);
  dim3 wpblk(32, 8, 1);
  k_wprep<<<wpgrid, wpblk, 0, stream>>>(Wq, Wkv, Wo, Wg, Wmix, wcat, wot);

  dim3 g1(NCPAD / 128, (B_ * N_) / 128);
  k_gemm97<<<g1, 256, 0, stream>>>(tokb, wcat, proj, B_ * N_, NCPAD, DIM_);

  k_post<<<B_ * N_, 256, 0, stream>>>(proj, vres, Qb, Kb, Vt, gates);

  k_attn<<<B_ * H_ * (N_ / 16), 64, 0, stream>>>(Qb, Kb, Vt, gates, Og);

  dim3 g2(DIM_ / 128, (B_ * N_) / 128);
  k_gemm97<<<g2, 256, 0, stream>>>(Og, wot, out, B_ * N_, DIM_, DI_);
}

// Round 3
// 108.491 us; speedup vs baseline: 1.1568x; 1.0748x over previous
//
#include <hip/hip_runtime.h>

#define B_ 2
#define N_ 2048
#define DIM_ 1024
#define H_ 8
#define DH_ 64
#define DI_ 512
#define WIN_ 512
#define NCPAD 1664  // 13*128 padded proj cols: 512 q | 1024 kv | 8 g | 8 mix | 112 pad

typedef __bf16 bf16x8 __attribute__((ext_vector_type(8)));
typedef unsigned short ushortx8 __attribute__((ext_vector_type(8)));
typedef float floatx4 __attribute__((ext_vector_type(4)));

__device__ inline unsigned short f2bf(float f) {
  union { float f; unsigned u; } v; v.f = f;
  unsigned r = v.u + 0x7FFFu + ((v.u >> 16) & 1u);
  return (unsigned short)(r >> 16);
}
__device__ inline float bf2f(unsigned short u) {
  union { unsigned u; float f; } v; v.u = ((unsigned)u) << 16; return v.f;
}
__device__ inline float sigmoidf_(float x) { return 1.0f / (1.0f + __expf(-x)); }

__device__ __forceinline__ void gload_lds16(const unsigned short* g, unsigned short* l) {
  __builtin_amdgcn_global_load_lds(
      (const __attribute__((address_space(1))) void*)g,
      (__attribute__((address_space(3))) void*)l,
      16, 0, 0);
}

// ---------------- prep: cos/sin table [N][32] ----------------
__global__ void k_trig(float2* __restrict__ cs) {
  int i = blockIdx.x * 256 + threadIdx.x;  // 65536
  int n = i >> 5, t2 = i & 31;
  float inv = __expf(-(float)t2 * 0.2878231366242557f);  // ln(10000)/32
  float sv, cv;
  sincosf((float)n * inv, &sv, &cv);
  cs[i] = make_float2(cv, sv);
}

// ---------------- prep: tokens fp32 -> bf16 ----------------
__global__ void k_tokens_bf16(const float* __restrict__ t, unsigned short* __restrict__ o, int n4) {
  int i = blockIdx.x * blockDim.x + threadIdx.x;
  if (i >= n4) return;
  float4 v = reinterpret_cast<const float4*>(t)[i];
  ushort4 r;
  r.x = f2bf(v.x); r.y = f2bf(v.y); r.z = f2bf(v.z); r.w = f2bf(v.w);
  reinterpret_cast<ushort4*>(o)[i] = r;
}

// ---------------- prep: coalesced LDS-tiled weight transposes ----------------
__global__ __launch_bounds__(256) void k_wprep(const float* __restrict__ Wq,
                                               const float* __restrict__ Wkv,
                                               const float* __restrict__ Wo,
                                               const float* __restrict__ Wg,
                                               const float* __restrict__ Wmix,
                                               unsigned short* __restrict__ wcat,
                                               unsigned short* __restrict__ wot) {
  const int z = blockIdx.z;
  const int tx = threadIdx.x, ty = threadIdx.y;
  if (z == 3) {
    int flat = blockIdx.y * gridDim.x + blockIdx.x;
    if (flat >= 64) return;
    int idx = flat * 256 + ty * 32 + tx;
    int j = idx >> 10;
    int c = idx & 1023;
    float v = (j < 8) ? Wg[c * 8 + j] : Wmix[c * 8 + (j - 8)];
    wcat[(size_t)(1536 + j) * 1024 + c] = f2bf(v);
    return;
  }
  const float* in;
  unsigned short* out;
  int Rin, Cin;
  if (z == 0)      { in = Wq;  out = wcat;              Rin = 1024; Cin = 512; }
  else if (z == 1) { in = Wkv; out = wcat + 512 * 1024; Rin = 1024; Cin = 1024; }
  else             { in = Wo;  out = wot;               Rin = 512;  Cin = 1024; }
  const int c0 = blockIdx.x * 32, r0 = blockIdx.y * 32;
  if (c0 >= Cin || r0 >= Rin) return;
  __shared__ float t[32][33];
#pragma unroll
  for (int i = 0; i < 4; ++i)
    t[ty + i * 8][tx] = in[(size_t)(r0 + ty + i * 8) * Cin + c0 + tx];
  __syncthreads();
#pragma unroll
  for (int i = 0; i < 4; ++i)
    out[(size_t)(c0 + ty + i * 8) * Rin + r0 + tx] = f2bf(t[tx][ty + i * 8]);
}

// ---------------- m97-structure GEMM, templated output ----------------
template <typename OUT>
__global__ __launch_bounds__(256) void k_gemm97(const unsigned short* __restrict__ A,
                                                const unsigned short* __restrict__ Bt,
                                                OUT* __restrict__ C,
                                                int M, int Nc, int K) {
  __shared__ __align__(16) unsigned short As[128 * 32];
  __shared__ __align__(16) unsigned short Bs[128 * 32];
  const int tid = threadIdx.x;
  const int lane = tid & 63;
  const int wid = tid >> 6;
  const int m0 = blockIdx.y * 128;
  const int n0 = blockIdx.x * 128;
  const int wr = (wid >> 1) * 64;
  const int wc = (wid & 1) * 64;
  const int lr = lane & 15;
  const int lk = (lane >> 4) << 3;
  const int srow = tid >> 2;
  const int scol = (tid & 3) << 3;
  const unsigned short* a0 = A + (size_t)(m0 + srow) * K + scol;
  const unsigned short* a1 = A + (size_t)(m0 + 64 + srow) * K + scol;
  const unsigned short* b0 = Bt + (size_t)(n0 + srow) * K + scol;
  const unsigned short* b1 = Bt + (size_t)(n0 + 64 + srow) * K + scol;
  unsigned short* lA0 = (unsigned short*)((char*)As + wid * 1024);
  unsigned short* lA1 = (unsigned short*)((char*)As + 4096 + wid * 1024);
  unsigned short* lB0 = (unsigned short*)((char*)Bs + wid * 1024);
  unsigned short* lB1 = (unsigned short*)((char*)Bs + 4096 + wid * 1024);
  floatx4 acc[4][4] = {};
  for (int k0 = 0; k0 < K; k0 += 32) {
    __syncthreads();
    gload_lds16(a0 + k0, lA0);
    gload_lds16(a1 + k0, lA1);
    gload_lds16(b0 + k0, lB0);
    gload_lds16(b1 + k0, lB1);
    __syncthreads();
    bf16x8 af[4], bfr[4];
#pragma unroll
    for (int i = 0; i < 4; ++i)
      af[i] = *reinterpret_cast<const bf16x8*>(&As[(wr + i * 16 + lr) * 32 + lk]);
#pragma unroll
    for (int j = 0; j < 4; ++j)
      bfr[j] = *reinterpret_cast<const bf16x8*>(&Bs[(wc + j * 16 + lr) * 32 + lk]);
#pragma unroll
    for (int i = 0; i < 4; ++i)
#pragma unroll
      for (int j = 0; j < 4; ++j)
        acc[i][j] = __builtin_amdgcn_mfma_f32_16x16x32_bf16(af[i], bfr[j], acc[i][j], 0, 0, 0);
  }
  const int r0 = (lane >> 4) << 2;
#pragma unroll
  for (int i = 0; i < 4; ++i)
#pragma unroll
    for (int j = 0; j < 4; ++j) {
      OUT* cp = C + (size_t)(m0 + wr + i * 16 + r0) * Nc + n0 + wc + j * 16 + lr;
#pragma unroll
      for (int r = 0; r < 4; ++r) {
        if constexpr (sizeof(OUT) == 4) cp[(size_t)r * Nc] = acc[i][j][r];
        else                            cp[(size_t)r * Nc] = f2bf(acc[i][j][r]);
      }
    }
}

// ---------------- post: RoPE (table), scale, Q/K bf16 coalesced, gates ----------------
__global__ __launch_bounds__(256) void k_post(const unsigned short* __restrict__ proj,
                                              const float2* __restrict__ cs,
                                              unsigned short* __restrict__ Qb,
                                              unsigned short* __restrict__ Kb,
                                              float* __restrict__ gates) {
  const int w = threadIdx.x >> 6, l = threadIdx.x & 63;
  const int row = blockIdx.x * 4 + w;
  const int b = row >> 11, n = row & (N_ - 1);
  const unsigned short* pr = proj + (size_t)row * NCPAD;
  if (l < H_) gates[(size_t)(b * H_ + l) * N_ + n] = sigmoidf_(bf2f(pr[1536 + l]));
  ushortx8 qv = *reinterpret_cast<const ushortx8*>(pr + 8 * l);
  ushortx8 kv = *reinterpret_cast<const ushortx8*>(pr + 512 + 8 * l);
  const int t2b = 4 * (l & 7);
  ushortx8 qo, ko;
#pragma unroll
  for (int p = 0; p < 4; ++p) {
    float2 c2 = cs[n * 32 + t2b + p];
    float q0 = bf2f(qv[2 * p]), q1 = bf2f(qv[2 * p + 1]);
    float k0 = bf2f(kv[2 * p]), k1 = bf2f(kv[2 * p + 1]);
    qo[2 * p]     = f2bf((q0 * c2.x - q1 * c2.y) * 0.125f);
    qo[2 * p + 1] = f2bf((q1 * c2.x + q0 * c2.y) * 0.125f);
    ko[2 * p]     = f2bf(k0 * c2.x - k1 * c2.y);
    ko[2 * p + 1] = f2bf(k1 * c2.x + k0 * c2.y);
  }
  const int h = l >> 3;
  const size_t off = ((size_t)(b * H_ + h) * N_ + n) * DH_ + 8 * (l & 7);
  *reinterpret_cast<ushortx8*>(Qb + off) = qo;
  *reinterpret_cast<ushortx8*>(Kb + off) = ko;
}

// ---------------- V: lerp + register-transpose into tiled [n/8][d][8] layout ----------------
__global__ __launch_bounds__(256) void k_vprep(const unsigned short* __restrict__ proj,
                                               const float* __restrict__ vres,
                                               unsigned short* __restrict__ Vt) {
  const int w = threadIdx.x >> 6, l = threadIdx.x & 63;
  const int bh = blockIdx.y;
  const int b = bh >> 3, h = bh & 7;
  const int n0 = blockIdx.x * 32 + w * 8;
  ushortx8 acc;
#pragma unroll
  for (int r = 0; r < 8; ++r) {
    const int n = n0 + r;
    const unsigned short* pr = proj + ((size_t)b * N_ + n) * NCPAD;
    const float mix = sigmoidf_(bf2f(pr[1544 + h]));
    const float pv = bf2f(pr[1024 + h * 64 + l]);
    const float vr = vres[((size_t)bh * N_ + n) * DH_ + l];
    acc[r] = f2bf(pv + (vr - pv) * mix);
  }
  // element (j,d) lives at Vt[bh*N*64 + (j>>3)*512 + d*8 + (j&7)]
  *reinterpret_cast<ushortx8*>(Vt + (size_t)bh * N_ * DH_ + (n0 >> 3) * 512 + l * 8) = acc;
}

// ---------------- windowed flash attention: static-max softmax ----------------
__global__ __launch_bounds__(64) void k_attn(const unsigned short* __restrict__ Qb,
                                             const unsigned short* __restrict__ Kb,
                                             const unsigned short* __restrict__ Vt,
                                             const float* __restrict__ gates,
                                             unsigned short* __restrict__ Og) {
  __shared__ __align__(16) unsigned short Plds[16 * 40];  // 80B rows: 16B-aligned, 4-way max conflict
  const int blk = blockIdx.x;
  const int bh = blk >> 7;
  const int qb = blk & 127;
  const int b = bh >> 3, h = bh & 7;
  const int qi0 = qb * 16;
  const int lane = threadIdx.x;
  const int lr = lane & 15;
  const int lk = (lane >> 4) << 3;
  const unsigned short* Qh = Qb + (size_t)bh * N_ * DH_;
  const unsigned short* Kh = Kb + (size_t)bh * N_ * DH_;
  const unsigned short* Vh = Vt + (size_t)bh * N_ * DH_;
  bf16x8 aq0 = *reinterpret_cast<const bf16x8*>(Qh + (qi0 + lr) * DH_ + lk);
  bf16x8 aq1 = *reinterpret_cast<const bf16x8*>(Qh + (qi0 + lr) * DH_ + 32 + lk);
  floatx4 o[4] = {};
  float lsum[4] = {0.f, 0.f, 0.f, 0.f};

  auto iter = [&](const int j0, const bool masked) {
    bf16x8 k00 = *reinterpret_cast<const bf16x8*>(Kh + (j0 + lr) * DH_ + lk);
    bf16x8 k01 = *reinterpret_cast<const bf16x8*>(Kh + (j0 + lr) * DH_ + 32 + lk);
    bf16x8 k10 = *reinterpret_cast<const bf16x8*>(Kh + (j0 + 16 + lr) * DH_ + lk);
    bf16x8 k11 = *reinterpret_cast<const bf16x8*>(Kh + (j0 + 16 + lr) * DH_ + 32 + lk);
    bf16x8 bv0 = *reinterpret_cast<const bf16x8*>(Vh + (j0 + lk) * DH_ + 0 * 128 + lr * 8);
    bf16x8 bv1 = *reinterpret_cast<const bf16x8*>(Vh + (j0 + lk) * DH_ + 1 * 128 + lr * 8);
    bf16x8 bv2 = *reinterpret_cast<const bf16x8*>(Vh + (j0 + lk) * DH_ + 2 * 128 + lr * 8);
    bf16x8 bv3 = *reinterpret_cast<const bf16x8*>(Vh + (j0 + lk) * DH_ + 3 * 128 + lr * 8);
    floatx4 c0 = {}, c1 = {};
    __builtin_amdgcn_s_setprio(1);
    c0 = __builtin_amdgcn_mfma_f32_16x16x32_bf16(aq0, k00, c0, 0, 0, 0);
    c0 = __builtin_amdgcn_mfma_f32_16x16x32_bf16(aq1, k01, c0, 0, 0, 0);
    c1 = __builtin_amdgcn_mfma_f32_16x16x32_bf16(aq0, k10, c1, 0, 0, 0);
    c1 = __builtin_amdgcn_mfma_f32_16x16x32_bf16(aq1, k11, c1, 0, 0, 0);
    __builtin_amdgcn_s_setprio(0);
#pragma unroll
    for (int r = 0; r < 4; ++r) {
      float s0 = c0[r], s1 = c1[r];
      if (masked) {
        const int i = qi0 + ((lane >> 4) << 2) + r;
        const unsigned d0 = (unsigned)(i - (j0 + lr));
        const unsigned d1 = (unsigned)(i - (j0 + 16 + lr));
        if (d0 > (unsigned)WIN_) s0 = -1e30f;
        if (d1 > (unsigned)WIN_) s1 = -1e30f;
      }
      const float p0 = __expf(s0);
      const float p1 = __expf(s1);
      lsum[r] += p0 + p1;
      const int prow = ((lane >> 4) << 2) + r;
      Plds[prow * 40 + lr] = f2bf(p0);
      Plds[prow * 40 + 16 + lr] = f2bf(p1);
    }
    __syncthreads();
    bf16x8 pa = *reinterpret_cast<const bf16x8*>(&Plds[lr * 40 + lk]);
    __builtin_amdgcn_s_setprio(1);
    o[0] = __builtin_amdgcn_mfma_f32_16x16x32_bf16(pa, bv0, o[0], 0, 0, 0);
    o[1] = __builtin_amdgcn_mfma_f32_16x16x32_bf16(pa, bv1, o[1], 0, 0, 0);
    o[2] = __builtin_amdgcn_mfma_f32_16x16x32_bf16(pa, bv2, o[2], 0, 0, 0);
    o[3] = __builtin_amdgcn_mfma_f32_16x16x32_bf16(pa, bv3, o[3], 0, 0, 0);
    __builtin_amdgcn_s_setprio(0);
    __syncthreads();
  };

  int jlo = 0;
  if (qi0 >= WIN_) {
    jlo = (qi0 - WIN_) & ~31;
    iter(jlo, true);
    jlo += 32;
  }
  const int jhi = (qi0 + 15) & ~31;
  for (int j0 = jlo; j0 < jhi; j0 += 32) iter(j0, false);
  iter(jhi, true);

#pragma unroll
  for (int r = 0; r < 4; ++r) {
    float ls = lsum[r];
#pragma unroll
    for (int off = 1; off < 16; off <<= 1) ls += __shfl_xor(ls, off, 16);
    const int i = qi0 + ((lane >> 4) << 2) + r;
    const float g = gates[(size_t)bh * N_ + i] * __builtin_amdgcn_rcpf(ls);
#pragma unroll
    for (int nb = 0; nb < 4; ++nb)
      Og[((size_t)(b * N_ + i)) * DI_ + h * DH_ + nb * 16 + lr] = f2bf(o[nb][r] * g);
  }
}

extern "C" void kernel_launch(void* const* d_in, const int* in_sizes, int n_in,
                              void* d_out, int out_size, void* d_ws, size_t ws_size,
                              hipStream_t stream) {
  const float* tokens = (const float*)d_in[0];
  const float* vres   = (const float*)d_in[1];
  const float* Wq     = (const float*)d_in[2];
  const float* Wkv    = (const float*)d_in[3];
  const float* Wo     = (const float*)d_in[4];
  const float* Wg     = (const float*)d_in[5];
  const float* Wmix   = (const float*)d_in[6];
  float* out = (float*)d_out;
  char* ws = (char*)d_ws;
  unsigned short* tokb = (unsigned short*)(ws);              // 8,388,608
  unsigned short* wcat = (unsigned short*)(ws + 8388608);    // 3,407,872
  unsigned short* wot  = (unsigned short*)(ws + 11796480);   // 1,048,576
  unsigned short* proj = (unsigned short*)(ws + 12845056);   // 4096*1664*2 = 13,631,488
  unsigned short* Qb   = (unsigned short*)(ws + 26476544);   // 4,194,304
  unsigned short* Kb   = (unsigned short*)(ws + 30670848);   // 4,194,304
  unsigned short* Vt   = (unsigned short*)(ws + 34865152);   // 4,194,304
  float*          gates= (float*)(ws + 39059456);            // 131,072
  unsigned short* Og   = (unsigned short*)(ws + 39190528);   // 4,194,304
  float2*         cs   = (float2*)(ws + 43384832);           // 524,288
  (void)in_sizes; (void)n_in; (void)out_size; (void)ws_size;

  k_trig<<<256, 256, 0, stream>>>(cs);
  k_tokens_bf16<<<4096, 256, 0, stream>>>(tokens, tokb, (B_ * N_ * DIM_) / 4);

  dim3 wpgrid(32, 32, 4);
  dim3 wpblk(32, 8, 1);
  k_wprep<<<wpgrid, wpblk, 0, stream>>>(Wq, Wkv, Wo, Wg, Wmix, wcat, wot);

  dim3 g1(NCPAD / 128, (B_ * N_) / 128);
  k_gemm97<unsigned short><<<g1, 256, 0, stream>>>(tokb, wcat, proj, B_ * N_, NCPAD, DIM_);

  k_post<<<(B_ * N_) / 4, 256, 0, stream>>>(proj, cs, Qb, Kb, gates);

  dim3 vg(64, 16);
  k_vprep<<<vg, 256, 0, stream>>>(proj, vres, Vt);

  k_attn<<<B_ * H_ * (N_ / 16), 64, 0, stream>>>(Qb, Kb, Vt, gates, Og);

  dim3 g2(DIM_ / 128, (B_ * N_) / 128);
  k_gemm97<float><<<g2, 256, 0, stream>>>(Og, wot, out, B_ * N_, DIM_, DI_);
}

// Round 4
// 85.602 us; speedup vs baseline: 1.4661x; 1.2674x over previous
//
#include <hip/hip_runtime.h>

#define B_ 2
#define N_ 2048
#define DIM_ 1024
#define H_ 8
#define DH_ 64
#define DI_ 512
#define WIN_ 512
#define NCPAD 1664  // 13*128 padded proj cols: 512 q | 1024 kv | 8 g | 8 mix | 112 pad

typedef __bf16 bf16x8 __attribute__((ext_vector_type(8)));
typedef unsigned short ushortx8 __attribute__((ext_vector_type(8)));
typedef float floatx4 __attribute__((ext_vector_type(4)));

__device__ inline unsigned short f2bf(float f) {
  union { float f; unsigned u; } v; v.f = f;
  unsigned r = v.u + 0x7FFFu + ((v.u >> 16) & 1u);
  return (unsigned short)(r >> 16);
}
__device__ inline float bf2f(unsigned short u) {
  union { unsigned u; float f; } v; v.u = ((unsigned)u) << 16; return v.f;
}
__device__ inline float sigmoidf_(float x) { return 1.0f / (1.0f + __expf(-x)); }

__device__ __forceinline__ void gload_lds16(const unsigned short* g, unsigned short* l) {
  __builtin_amdgcn_global_load_lds(
      (const __attribute__((address_space(1))) void*)g,
      (__attribute__((address_space(3))) void*)l,
      16, 0, 0);
}

// ================= fused prep: trig table | tokens->bf16 | weight transposes =================
// blocks: [0,256) trig | [256,4352) tokens | [4352,4864) Wq | [4864,5888) Wkv | [5888,6400) Wo | [6400,6464) strip
__global__ __launch_bounds__(256) void k_prep(const float* __restrict__ tokens,
                                              const float* __restrict__ Wq,
                                              const float* __restrict__ Wkv,
                                              const float* __restrict__ Wo,
                                              const float* __restrict__ Wg,
                                              const float* __restrict__ Wmix,
                                              unsigned short* __restrict__ tokb,
                                              unsigned short* __restrict__ wcat,
                                              unsigned short* __restrict__ wot,
                                              float2* __restrict__ cs) {
  __shared__ float t32[32][33];
  const int bid = blockIdx.x;
  const int tid = threadIdx.x;
  if (bid < 256) {
    int i = bid * 256 + tid;
    int n = i >> 5, t2 = i & 31;
    float inv = __expf(-(float)t2 * 0.2878231366242557f);  // ln(10000)/32
    float sv, cv;
    sincosf((float)n * inv, &sv, &cv);
    cs[i] = make_float2(cv, sv);
    return;
  }
  if (bid < 4352) {
    int i = (bid - 256) * 256 + tid;
    float4 v = reinterpret_cast<const float4*>(tokens)[i];
    ushort4 r;
    r.x = f2bf(v.x); r.y = f2bf(v.y); r.z = f2bf(v.z); r.w = f2bf(v.w);
    reinterpret_cast<ushort4*>(tokb)[i] = r;
    return;
  }
  if (bid >= 6400) {
    int idx = (bid - 6400) * 256 + tid;  // [0,16384)
    int j = idx >> 10;
    int c = idx & 1023;
    float v = (j < 8) ? Wg[c * 8 + j] : Wmix[c * 8 + (j - 8)];
    wcat[(size_t)(1536 + j) * 1024 + c] = f2bf(v);
    return;
  }
  const float* in;
  unsigned short* out;
  int Rin, Cin, c0, r0;
  if (bid < 4864) {
    int t = bid - 4352; in = Wq; out = wcat; Rin = 1024; Cin = 512;
    c0 = (t & 15) * 32; r0 = (t >> 4) * 32;
  } else if (bid < 5888) {
    int t = bid - 4864; in = Wkv; out = wcat + 512 * 1024; Rin = 1024; Cin = 1024;
    c0 = (t & 31) * 32; r0 = (t >> 5) * 32;
  } else {
    int t = bid - 5888; in = Wo; out = wot; Rin = 512; Cin = 1024;
    c0 = (t & 31) * 32; r0 = (t >> 5) * 32;
  }
  const int tx = tid & 31, ty = tid >> 5;
#pragma unroll
  for (int i = 0; i < 4; ++i)
    t32[ty + i * 8][tx] = in[(size_t)(r0 + ty + i * 8) * Cin + c0 + tx];
  __syncthreads();
#pragma unroll
  for (int i = 0; i < 4; ++i)
    out[(size_t)(c0 + ty + i * 8) * Rin + r0 + tx] = f2bf(t32[tx][ty + i * 8]);
}

// ================= BK=64 MFMA GEMM: C = A(bf16 [M][K]) * Bt(bf16 [Nc][K])^T =================
template <typename OUT>
__global__ __launch_bounds__(256) void k_gemm64(const unsigned short* __restrict__ A,
                                                const unsigned short* __restrict__ Bt,
                                                OUT* __restrict__ C,
                                                int M, int Nc, int K) {
  __shared__ __align__(16) unsigned short As[128 * 64];
  __shared__ __align__(16) unsigned short Bs[128 * 64];
  const int tid = threadIdx.x;
  const int lane = tid & 63;
  const int wid = tid >> 6;
  const int m0 = blockIdx.y * 128;
  const int n0 = blockIdx.x * 128;
  const int wr = (wid >> 1) * 64;
  const int wc = (wid & 1) * 64;
  const int lr = lane & 15;
  const int lk = (lane >> 4) << 3;
  const int grow = tid >> 3;        // 0..31
  const int gcol = (tid & 7) << 3;  // 0,8,..,56
  const unsigned short* aP = A + (size_t)(m0 + grow) * K + gcol;
  const unsigned short* bP = Bt + (size_t)(n0 + grow) * K + gcol;
  unsigned short* lA = As + grow * 64 + gcol;  // per-wave: base + lane*16B (linear) per 32-row round
  unsigned short* lB = Bs + grow * 64 + gcol;
  floatx4 acc[4][4] = {};
  for (int k0 = 0; k0 < K; k0 += 64) {
    __syncthreads();
#pragma unroll
    for (int r = 0; r < 4; ++r) gload_lds16(aP + k0 + (size_t)(r * 32) * K, lA + r * 2048);
#pragma unroll
    for (int r = 0; r < 4; ++r) gload_lds16(bP + k0 + (size_t)(r * 32) * K, lB + r * 2048);
    __syncthreads();
#pragma unroll
    for (int kk = 0; kk < 2; ++kk) {
      bf16x8 af[4], bfr[4];
#pragma unroll
      for (int i = 0; i < 4; ++i)
        af[i] = *reinterpret_cast<const bf16x8*>(&As[(wr + i * 16 + lr) * 64 + kk * 32 + lk]);
#pragma unroll
      for (int j = 0; j < 4; ++j)
        bfr[j] = *reinterpret_cast<const bf16x8*>(&Bs[(wc + j * 16 + lr) * 64 + kk * 32 + lk]);
#pragma unroll
      for (int i = 0; i < 4; ++i)
#pragma unroll
        for (int j = 0; j < 4; ++j)
          acc[i][j] = __builtin_amdgcn_mfma_f32_16x16x32_bf16(af[i], bfr[j], acc[i][j], 0, 0, 0);
    }
  }
  const int r0 = (lane >> 4) << 2;
#pragma unroll
  for (int i = 0; i < 4; ++i)
#pragma unroll
    for (int j = 0; j < 4; ++j) {
      OUT* cp = C + (size_t)(m0 + wr + i * 16 + r0) * Nc + n0 + wc + j * 16 + lr;
#pragma unroll
      for (int r = 0; r < 4; ++r) {
        if constexpr (sizeof(OUT) == 4) cp[(size_t)r * Nc] = acc[i][j][r];
        else                            cp[(size_t)r * Nc] = f2bf(acc[i][j][r]);
      }
    }
}

// ================= fused post: RoPE Q/K + gates + V lerp/tile (8 rows per block) =================
__global__ __launch_bounds__(512) void k_postv(const unsigned short* __restrict__ proj,
                                               const float* __restrict__ vres,
                                               const float2* __restrict__ cs,
                                               unsigned short* __restrict__ Qb,
                                               unsigned short* __restrict__ Kb,
                                               unsigned short* __restrict__ Vt,
                                               float* __restrict__ gates) {
  const int w = threadIdx.x >> 6, l = threadIdx.x & 63;
  const int row = blockIdx.x * 8 + w;
  const int b = row >> 11, n = row & (N_ - 1);
  const unsigned short* pr = proj + (size_t)row * NCPAD;
  if (l < H_) gates[(size_t)(b * H_ + l) * N_ + n] = sigmoidf_(bf2f(pr[1536 + l]));
  ushortx8 qv = *reinterpret_cast<const ushortx8*>(pr + 8 * l);
  ushortx8 kv = *reinterpret_cast<const ushortx8*>(pr + 512 + 8 * l);
  const int t2b = 4 * (l & 7);
  ushortx8 qo, ko;
#pragma unroll
  for (int p = 0; p < 4; ++p) {
    float2 c2 = cs[n * 32 + t2b + p];
    float q0 = bf2f(qv[2 * p]), q1 = bf2f(qv[2 * p + 1]);
    float k0 = bf2f(kv[2 * p]), k1 = bf2f(kv[2 * p + 1]);
    qo[2 * p]     = f2bf((q0 * c2.x - q1 * c2.y) * 0.125f);
    qo[2 * p + 1] = f2bf((q1 * c2.x + q0 * c2.y) * 0.125f);
    ko[2 * p]     = f2bf(k0 * c2.x - k1 * c2.y);
    ko[2 * p + 1] = f2bf(k1 * c2.x + k0 * c2.y);
  }
  const int h = l >> 3;
  const size_t off = ((size_t)(b * H_ + h) * N_ + n) * DH_ + 8 * (l & 7);
  *reinterpret_cast<ushortx8*>(Qb + off) = qo;
  *reinterpret_cast<ushortx8*>(Kb + off) = ko;
  // ---- V part: wave w handles head hv=w, lanes are d; 8 rows gathered into one 16B tile store
  const int hv = w;
  const int d = l;
  const int base_row = blockIdx.x * 8;
  const int bb = base_row >> 11;
  ushortx8 acc;
#pragma unroll
  for (int r = 0; r < 8; ++r) {
    const unsigned short* pr2 = proj + (size_t)(base_row + r) * NCPAD;
    const float mix = sigmoidf_(bf2f(pr2[1544 + hv]));
    const float pv = bf2f(pr2[1024 + hv * 64 + d]);
    const float vr = vres[((size_t)(bb * H_ + hv) * N_ + ((base_row + r) & (N_ - 1))) * DH_ + d];
    acc[r] = f2bf(pv + (vr - pv) * mix);
  }
  // element (j,d) of head hv lives at Vt[bh*N*64 + (jlocal>>3)*512 + d*8 + (j&7)]
  *reinterpret_cast<ushortx8*>(Vt + (size_t)(bb * H_ + hv) * N_ * DH_ +
                               (size_t)(blockIdx.x & 255) * 512 + d * 8) = acc;
}

// ================= windowed flash attention: static-max softmax, XCD-chunked =================
__global__ __launch_bounds__(64) void k_attn(const unsigned short* __restrict__ Qb,
                                             const unsigned short* __restrict__ Kb,
                                             const unsigned short* __restrict__ Vt,
                                             const float* __restrict__ gates,
                                             unsigned short* __restrict__ Og) {
  __shared__ __align__(16) unsigned short Plds[16 * 40];
  const int blk = (blockIdx.x & 7) * 256 + (blockIdx.x >> 3);  // XCD-chunked (2048 % 8 == 0)
  const int bh = blk >> 7;
  const int qb = blk & 127;
  const int b = bh >> 3, h = bh & 7;
  const int qi0 = qb * 16;
  const int lane = threadIdx.x;
  const int lr = lane & 15;
  const int lk = (lane >> 4) << 3;
  const unsigned short* Qh = Qb + (size_t)bh * N_ * DH_;
  const unsigned short* Kh = Kb + (size_t)bh * N_ * DH_;
  const unsigned short* Vh = Vt + (size_t)bh * N_ * DH_;
  bf16x8 aq0 = *reinterpret_cast<const bf16x8*>(Qh + (qi0 + lr) * DH_ + lk);
  bf16x8 aq1 = *reinterpret_cast<const bf16x8*>(Qh + (qi0 + lr) * DH_ + 32 + lk);
  floatx4 o[4] = {};
  float lsum[4] = {0.f, 0.f, 0.f, 0.f};

  auto iter = [&](const int j0, const bool masked) {
    bf16x8 k00 = *reinterpret_cast<const bf16x8*>(Kh + (j0 + lr) * DH_ + lk);
    bf16x8 k01 = *reinterpret_cast<const bf16x8*>(Kh + (j0 + lr) * DH_ + 32 + lk);
    bf16x8 k10 = *reinterpret_cast<const bf16x8*>(Kh + (j0 + 16 + lr) * DH_ + lk);
    bf16x8 k11 = *reinterpret_cast<const bf16x8*>(Kh + (j0 + 16 + lr) * DH_ + 32 + lk);
    bf16x8 bv0 = *reinterpret_cast<const bf16x8*>(Vh + (j0 + lk) * DH_ + 0 * 128 + lr * 8);
    bf16x8 bv1 = *reinterpret_cast<const bf16x8*>(Vh + (j0 + lk) * DH_ + 1 * 128 + lr * 8);
    bf16x8 bv2 = *reinterpret_cast<const bf16x8*>(Vh + (j0 + lk) * DH_ + 2 * 128 + lr * 8);
    bf16x8 bv3 = *reinterpret_cast<const bf16x8*>(Vh + (j0 + lk) * DH_ + 3 * 128 + lr * 8);
    floatx4 c0 = {}, c1 = {};
    __builtin_amdgcn_s_setprio(1);
    c0 = __builtin_amdgcn_mfma_f32_16x16x32_bf16(aq0, k00, c0, 0, 0, 0);
    c0 = __builtin_amdgcn_mfma_f32_16x16x32_bf16(aq1, k01, c0, 0, 0, 0);
    c1 = __builtin_amdgcn_mfma_f32_16x16x32_bf16(aq0, k10, c1, 0, 0, 0);
    c1 = __builtin_amdgcn_mfma_f32_16x16x32_bf16(aq1, k11, c1, 0, 0, 0);
    __builtin_amdgcn_s_setprio(0);
#pragma unroll
    for (int r = 0; r < 4; ++r) {
      float s0 = c0[r], s1 = c1[r];
      if (masked) {
        const int i = qi0 + ((lane >> 4) << 2) + r;
        const unsigned d0 = (unsigned)(i - (j0 + lr));
        const unsigned d1 = (unsigned)(i - (j0 + 16 + lr));
        if (d0 > (unsigned)WIN_) s0 = -1e30f;
        if (d1 > (unsigned)WIN_) s1 = -1e30f;
      }
      const float p0 = __expf(s0);
      const float p1 = __expf(s1);
      lsum[r] += p0 + p1;
      const int prow = ((lane >> 4) << 2) + r;
      Plds[prow * 40 + lr] = f2bf(p0);
      Plds[prow * 40 + 16 + lr] = f2bf(p1);
    }
    __syncthreads();
    bf16x8 pa = *reinterpret_cast<const bf16x8*>(&Plds[lr * 40 + lk]);
    __builtin_amdgcn_s_setprio(1);
    o[0] = __builtin_amdgcn_mfma_f32_16x16x32_bf16(pa, bv0, o[0], 0, 0, 0);
    o[1] = __builtin_amdgcn_mfma_f32_16x16x32_bf16(pa, bv1, o[1], 0, 0, 0);
    o[2] = __builtin_amdgcn_mfma_f32_16x16x32_bf16(pa, bv2, o[2], 0, 0, 0);
    o[3] = __builtin_amdgcn_mfma_f32_16x16x32_bf16(pa, bv3, o[3], 0, 0, 0);
    __builtin_amdgcn_s_setprio(0);
    __syncthreads();
  };

  int jlo = 0;
  if (qi0 >= WIN_) {
    jlo = (qi0 - WIN_) & ~31;
    iter(jlo, true);
    jlo += 32;
  }
  const int jhi = (qi0 + 15) & ~31;
  for (int j0 = jlo; j0 < jhi; j0 += 32) iter(j0, false);
  iter(jhi, true);

#pragma unroll
  for (int r = 0; r < 4; ++r) {
    float ls = lsum[r];
#pragma unroll
    for (int off = 1; off < 16; off <<= 1) ls += __shfl_xor(ls, off, 16);
    const int i = qi0 + ((lane >> 4) << 2) + r;
    const float g = gates[(size_t)bh * N_ + i] * __builtin_amdgcn_rcpf(ls);
#pragma unroll
    for (int nb = 0; nb < 4; ++nb)
      Og[((size_t)(b * N_ + i)) * DI_ + h * DH_ + nb * 16 + lr] = f2bf(o[nb][r] * g);
  }
}

extern "C" void kernel_launch(void* const* d_in, const int* in_sizes, int n_in,
                              void* d_out, int out_size, void* d_ws, size_t ws_size,
                              hipStream_t stream) {
  const float* tokens = (const float*)d_in[0];
  const float* vres   = (const float*)d_in[1];
  const float* Wq     = (const float*)d_in[2];
  const float* Wkv    = (const float*)d_in[3];
  const float* Wo     = (const float*)d_in[4];
  const float* Wg     = (const float*)d_in[5];
  const float* Wmix   = (const float*)d_in[6];
  float* out = (float*)d_out;
  char* ws = (char*)d_ws;
  unsigned short* tokb = (unsigned short*)(ws);              // 8,388,608
  unsigned short* wcat = (unsigned short*)(ws + 8388608);    // 3,407,872
  unsigned short* wot  = (unsigned short*)(ws + 11796480);   // 1,048,576
  unsigned short* proj = (unsigned short*)(ws + 12845056);   // 13,631,488
  unsigned short* Qb   = (unsigned short*)(ws + 26476544);   // 4,194,304
  unsigned short* Kb   = (unsigned short*)(ws + 30670848);   // 4,194,304
  unsigned short* Vt   = (unsigned short*)(ws + 34865152);   // 4,194,304
  float*          gates= (float*)(ws + 39059456);            // 131,072
  unsigned short* Og   = (unsigned short*)(ws + 39190528);   // 4,194,304
  float2*         cs   = (float2*)(ws + 43384832);           // 524,288
  (void)in_sizes; (void)n_in; (void)out_size; (void)ws_size;

  k_prep<<<6464, 256, 0, stream>>>(tokens, Wq, Wkv, Wo, Wg, Wmix, tokb, wcat, wot, cs);

  dim3 g1(NCPAD / 128, (B_ * N_) / 128);
  k_gemm64<unsigned short><<<g1, 256, 0, stream>>>(tokb, wcat, proj, B_ * N_, NCPAD, DIM_);

  k_postv<<<(B_ * N_) / 8, 512, 0, stream>>>(proj, vres, cs, Qb, Kb, Vt, gates);

  k_attn<<<B_ * H_ * (N_ / 16), 64, 0, stream>>>(Qb, Kb, Vt, gates, Og);

  dim3 g2(DIM_ / 128, (B_ * N_) / 128);
  k_gemm64<float><<<g2, 256, 0, stream>>>(Og, wot, out, B_ * N_, DIM_, DI_);
}

// Round 5
// 77.491 us; speedup vs baseline: 1.6195x; 1.1047x over previous
//
#include <hip/hip_runtime.h>

#define B_ 2
#define N_ 2048
#define DIM_ 1024
#define H_ 8
#define DH_ 64
#define DI_ 512
#define WIN_ 512
#define NCPAD 1664  // 13*128 padded proj cols: 512 q | 1024 kv | 8 g | 8 mix | 112 pad

typedef __bf16 bf16x8 __attribute__((ext_vector_type(8)));
typedef unsigned short ushortx8 __attribute__((ext_vector_type(8)));
typedef float floatx4 __attribute__((ext_vector_type(4)));

#define MFMA16(a, b, c) __builtin_amdgcn_mfma_f32_16x16x32_bf16((a), (b), (c), 0, 0, 0)

__device__ inline unsigned short f2bf(float f) {
  union { float f; unsigned u; } v; v.f = f;
  unsigned r = v.u + 0x7FFFu + ((v.u >> 16) & 1u);
  return (unsigned short)(r >> 16);
}
__device__ inline float bf2f(unsigned short u) {
  union { unsigned u; float f; } v; v.u = ((unsigned)u) << 16; return v.f;
}
__device__ inline float sigmoidf_(float x) { return 1.0f / (1.0f + __expf(-x)); }

__device__ __forceinline__ void gload_lds16(const unsigned short* g, unsigned short* l) {
  __builtin_amdgcn_global_load_lds(
      (const __attribute__((address_space(1))) void*)g,
      (__attribute__((address_space(3))) void*)l,
      16, 0, 0);
}

// ================= fused prep: trig table | tokens->bf16 | weight transposes =================
__global__ __launch_bounds__(256) void k_prep(const float* __restrict__ tokens,
                                              const float* __restrict__ Wq,
                                              const float* __restrict__ Wkv,
                                              const float* __restrict__ Wo,
                                              const float* __restrict__ Wg,
                                              const float* __restrict__ Wmix,
                                              unsigned short* __restrict__ tokb,
                                              unsigned short* __restrict__ wcat,
                                              unsigned short* __restrict__ wot,
                                              float2* __restrict__ cs) {
  __shared__ float t32[32][33];
  const int bid = blockIdx.x;
  const int tid = threadIdx.x;
  if (bid < 256) {
    int i = bid * 256 + tid;
    int n = i >> 5, t2 = i & 31;
    float inv = __expf(-(float)t2 * 0.2878231366242557f);  // ln(10000)/32
    float sv, cv;
    sincosf((float)n * inv, &sv, &cv);
    cs[i] = make_float2(cv, sv);
    return;
  }
  if (bid < 4352) {
    int i = (bid - 256) * 256 + tid;
    float4 v = reinterpret_cast<const float4*>(tokens)[i];
    ushort4 r;
    r.x = f2bf(v.x); r.y = f2bf(v.y); r.z = f2bf(v.z); r.w = f2bf(v.w);
    reinterpret_cast<ushort4*>(tokb)[i] = r;
    return;
  }
  if (bid >= 6400) {
    int idx = (bid - 6400) * 256 + tid;
    int j = idx >> 10;
    int c = idx & 1023;
    float v = (j < 8) ? Wg[c * 8 + j] : Wmix[c * 8 + (j - 8)];
    wcat[(size_t)(1536 + j) * 1024 + c] = f2bf(v);
    return;
  }
  const float* in;
  unsigned short* out;
  int Rin, Cin, c0, r0;
  if (bid < 4864) {
    int t = bid - 4352; in = Wq; out = wcat; Rin = 1024; Cin = 512;
    c0 = (t & 15) * 32; r0 = (t >> 4) * 32;
  } else if (bid < 5888) {
    int t = bid - 4864; in = Wkv; out = wcat + 512 * 1024; Rin = 1024; Cin = 1024;
    c0 = (t & 31) * 32; r0 = (t >> 5) * 32;
  } else {
    int t = bid - 5888; in = Wo; out = wot; Rin = 512; Cin = 1024;
    c0 = (t & 31) * 32; r0 = (t >> 5) * 32;
  }
  const int tx = tid & 31, ty = tid >> 5;
#pragma unroll
  for (int i = 0; i < 4; ++i)
    t32[ty + i * 8][tx] = in[(size_t)(r0 + ty + i * 8) * Cin + c0 + tx];
  __syncthreads();
#pragma unroll
  for (int i = 0; i < 4; ++i)
    out[(size_t)(c0 + ty + i * 8) * Rin + r0 + tx] = f2bf(t32[tx][ty + i * 8]);
}

// ================= BK=64 MFMA GEMM: C = A(bf16 [M][K]) * Bt(bf16 [Nc][K])^T =================
template <typename OUT>
__global__ __launch_bounds__(256) void k_gemm64(const unsigned short* __restrict__ A,
                                                const unsigned short* __restrict__ Bt,
                                                OUT* __restrict__ C,
                                                int M, int Nc, int K) {
  __shared__ __align__(16) unsigned short As[128 * 64];
  __shared__ __align__(16) unsigned short Bs[128 * 64];
  const int tid = threadIdx.x;
  const int lane = tid & 63;
  const int wid = tid >> 6;
  const int m0 = blockIdx.y * 128;
  const int n0 = blockIdx.x * 128;
  const int wr = (wid >> 1) * 64;
  const int wc = (wid & 1) * 64;
  const int lr = lane & 15;
  const int lk = (lane >> 4) << 3;
  const int grow = tid >> 3;
  const int gcol = (tid & 7) << 3;
  const unsigned short* aP = A + (size_t)(m0 + grow) * K + gcol;
  const unsigned short* bP = Bt + (size_t)(n0 + grow) * K + gcol;
  unsigned short* lA = As + grow * 64 + gcol;
  unsigned short* lB = Bs + grow * 64 + gcol;
  floatx4 acc[4][4] = {};
  for (int k0 = 0; k0 < K; k0 += 64) {
    __syncthreads();
#pragma unroll
    for (int r = 0; r < 4; ++r) gload_lds16(aP + k0 + (size_t)(r * 32) * K, lA + r * 2048);
#pragma unroll
    for (int r = 0; r < 4; ++r) gload_lds16(bP + k0 + (size_t)(r * 32) * K, lB + r * 2048);
    __syncthreads();
#pragma unroll
    for (int kk = 0; kk < 2; ++kk) {
      bf16x8 af[4], bfr[4];
#pragma unroll
      for (int i = 0; i < 4; ++i)
        af[i] = *reinterpret_cast<const bf16x8*>(&As[(wr + i * 16 + lr) * 64 + kk * 32 + lk]);
#pragma unroll
      for (int j = 0; j < 4; ++j)
        bfr[j] = *reinterpret_cast<const bf16x8*>(&Bs[(wc + j * 16 + lr) * 64 + kk * 32 + lk]);
#pragma unroll
      for (int i = 0; i < 4; ++i)
#pragma unroll
        for (int j = 0; j < 4; ++j)
          acc[i][j] = MFMA16(af[i], bfr[j], acc[i][j]);
    }
  }
  const int r0 = (lane >> 4) << 2;
#pragma unroll
  for (int i = 0; i < 4; ++i)
#pragma unroll
    for (int j = 0; j < 4; ++j) {
      OUT* cp = C + (size_t)(m0 + wr + i * 16 + r0) * Nc + n0 + wc + j * 16 + lr;
#pragma unroll
      for (int r = 0; r < 4; ++r) {
        if constexpr (sizeof(OUT) == 4) cp[(size_t)r * Nc] = acc[i][j][r];
        else                            cp[(size_t)r * Nc] = f2bf(acc[i][j][r]);
      }
    }
}

// ================= fused post: RoPE Q/K + gates + V lerp/tile =================
__global__ __launch_bounds__(512) void k_postv(const unsigned short* __restrict__ proj,
                                               const float* __restrict__ vres,
                                               const float2* __restrict__ cs,
                                               unsigned short* __restrict__ Qb,
                                               unsigned short* __restrict__ Kb,
                                               unsigned short* __restrict__ Vt,
                                               float* __restrict__ gates) {
  const int w = threadIdx.x >> 6, l = threadIdx.x & 63;
  const int row = blockIdx.x * 8 + w;
  const int b = row >> 11, n = row & (N_ - 1);
  const unsigned short* pr = proj + (size_t)row * NCPAD;
  if (l < H_) gates[(size_t)(b * H_ + l) * N_ + n] = sigmoidf_(bf2f(pr[1536 + l]));
  ushortx8 qv = *reinterpret_cast<const ushortx8*>(pr + 8 * l);
  ushortx8 kv = *reinterpret_cast<const ushortx8*>(pr + 512 + 8 * l);
  const int t2b = 4 * (l & 7);
  ushortx8 qo, ko;
#pragma unroll
  for (int p = 0; p < 4; ++p) {
    float2 c2 = cs[n * 32 + t2b + p];
    float q0 = bf2f(qv[2 * p]), q1 = bf2f(qv[2 * p + 1]);
    float k0 = bf2f(kv[2 * p]), k1 = bf2f(kv[2 * p + 1]);
    qo[2 * p]     = f2bf((q0 * c2.x - q1 * c2.y) * 0.125f);
    qo[2 * p + 1] = f2bf((q1 * c2.x + q0 * c2.y) * 0.125f);
    ko[2 * p]     = f2bf(k0 * c2.x - k1 * c2.y);
    ko[2 * p + 1] = f2bf(k1 * c2.x + k0 * c2.y);
  }
  const int h = l >> 3;
  const size_t off = ((size_t)(b * H_ + h) * N_ + n) * DH_ + 8 * (l & 7);
  *reinterpret_cast<ushortx8*>(Qb + off) = qo;
  *reinterpret_cast<ushortx8*>(Kb + off) = ko;
  const int hv = w;
  const int d = l;
  const int base_row = blockIdx.x * 8;
  const int bb = base_row >> 11;
  ushortx8 acc;
#pragma unroll
  for (int r = 0; r < 8; ++r) {
    const unsigned short* pr2 = proj + (size_t)(base_row + r) * NCPAD;
    const float mix = sigmoidf_(bf2f(pr2[1544 + hv]));
    const float pv = bf2f(pr2[1024 + hv * 64 + d]);
    const float vr = vres[((size_t)(bb * H_ + hv) * N_ + ((base_row + r) & (N_ - 1))) * DH_ + d];
    acc[r] = f2bf(pv + (vr - pv) * mix);
  }
  *reinterpret_cast<ushortx8*>(Vt + (size_t)(bb * H_ + hv) * N_ * DH_ +
                               (size_t)(blockIdx.x & 255) * 512 + d * 8) = acc;
}

// ================= 4-wave LDS-staged windowed attention =================
// block = 64 queries (4 waves x 16), KV tiles of 64 keys double-buffered in LDS.
// K staged with XOR swizzle (chunk ^= row&7) via pre-swizzled global source.
__global__ __launch_bounds__(256) void k_attn4(const unsigned short* __restrict__ Qb,
                                               const unsigned short* __restrict__ Kb,
                                               const unsigned short* __restrict__ Vt,
                                               const float* __restrict__ gates,
                                               unsigned short* __restrict__ Og) {
  __shared__ __align__(16) unsigned short Ks[2][64 * 64];
  __shared__ __align__(16) unsigned short Vs[2][64 * 64];
  __shared__ __align__(16) unsigned short Ps[4][16 * 72];  // 144B rows: 16B-aligned, 2-way banks
  const int bid = (int)blockIdx.x;
  const int blk = (bid & 7) * 64 + (bid >> 3);  // XCD-chunked: 512 blocks, 2 heads/XCD
  const int bh = blk >> 5;
  const int qt = blk & 31;
  const int b = bh >> 3, h = bh & 7;
  const int qi0 = qt * 64;
  const int tid = threadIdx.x;
  const int w = tid >> 6;
  const int lane = tid & 63;
  const int lr = lane & 15;
  const int hi = lane >> 4;
  const int lk = hi << 3;
  const int qw0 = qi0 + w * 16;
  const unsigned short* Qh = Qb + (size_t)bh * N_ * DH_;
  const unsigned short* Kh = Kb + (size_t)bh * N_ * DH_;
  const unsigned short* Vh = Vt + (size_t)bh * N_ * DH_;
  bf16x8 aq0 = *reinterpret_cast<const bf16x8*>(Qh + (qw0 + lr) * DH_ + lk);
  bf16x8 aq1 = *reinterpret_cast<const bf16x8*>(Qh + (qw0 + lr) * DH_ + 32 + lk);
  floatx4 o[4] = {};
  float lsum[4] = {0.f, 0.f, 0.f, 0.f};

  const int s_row = tid >> 3;   // 0..31
  const int s_chk = tid & 7;    // 16B chunk within 128B row

  auto stage = [&](int bufi, int j0) {
#pragma unroll
    for (int p = 0; p < 2; ++p) {
      const int row = s_row + p * 32;
      const int csw = s_chk ^ (row & 7);
      gload_lds16(Kh + (size_t)(j0 + row) * DH_ + csw * 8, &Ks[bufi][(row * 8 + s_chk) * 8]);
    }
#pragma unroll
    for (int p = 0; p < 2; ++p) {
      const int flat = p * 256 + tid;
      gload_lds16(Vh + (size_t)j0 * DH_ + flat * 8, &Vs[bufi][flat * 8]);
    }
  };

  auto compute = [&](int bufi, int j0) {
    floatx4 c[4];
    __builtin_amdgcn_s_setprio(1);
#pragma unroll
    for (int cc = 0; cc < 4; ++cc) {
      const int row = 16 * cc + lr;
      const int sw = row & 7;
      bf16x8 kf0 = *reinterpret_cast<const bf16x8*>(&Ks[bufi][row * 64 + (((lk >> 3) ^ sw) << 3)]);
      bf16x8 kf1 = *reinterpret_cast<const bf16x8*>(&Ks[bufi][row * 64 + ((((lk >> 3) + 4) ^ sw) << 3)]);
      floatx4 a = {};
      a = MFMA16(aq0, kf0, a);
      a = MFMA16(aq1, kf1, a);
      c[cc] = a;
    }
    __builtin_amdgcn_s_setprio(0);
#pragma unroll
    for (int cc = 0; cc < 4; ++cc)
#pragma unroll
      for (int r = 0; r < 4; ++r) {
        const int i = qw0 + hi * 4 + r;
        const int j = j0 + 16 * cc + lr;
        float s = c[cc][r];
        const unsigned dd = (unsigned)(i - j);
        if (dd > (unsigned)WIN_) s = -1e30f;
        const float p = __expf(s);
        lsum[r] += p;
        Ps[w][(hi * 4 + r) * 72 + 16 * cc + lr] = f2bf(p);
      }
    bf16x8 pa0 = *reinterpret_cast<const bf16x8*>(&Ps[w][lr * 72 + lk]);
    bf16x8 pa1 = *reinterpret_cast<const bf16x8*>(&Ps[w][lr * 72 + 32 + lk]);
    __builtin_amdgcn_s_setprio(1);
#pragma unroll
    for (int nb = 0; nb < 4; ++nb) {
      bf16x8 v0 = *reinterpret_cast<const bf16x8*>(&Vs[bufi][lk * 64 + nb * 128 + lr * 8]);
      bf16x8 v1 = *reinterpret_cast<const bf16x8*>(&Vs[bufi][(32 + lk) * 64 + nb * 128 + lr * 8]);
      o[nb] = MFMA16(pa0, v0, o[nb]);
      o[nb] = MFMA16(pa1, v1, o[nb]);
    }
    __builtin_amdgcn_s_setprio(0);
  };

  const int jlo = (qi0 >= WIN_) ? (qi0 - WIN_) : 0;
  const int niter = (qi0 + 64 - jlo) >> 6;

  stage(0, jlo);
  __syncthreads();
  int bufi = 0;
  for (int t = 0; t < niter; ++t) {
    const int j0 = jlo + t * 64;
    if (t + 1 < niter) stage(bufi ^ 1, j0 + 64);
    compute(bufi, j0);
    __syncthreads();
    bufi ^= 1;
  }

#pragma unroll
  for (int r = 0; r < 4; ++r) {
    float ls = lsum[r];
#pragma unroll
    for (int off = 1; off < 16; off <<= 1) ls += __shfl_xor(ls, off, 16);
    const int i = qw0 + hi * 4 + r;
    const float g = gates[(size_t)bh * N_ + i] * __builtin_amdgcn_rcpf(ls);
#pragma unroll
    for (int nb = 0; nb < 4; ++nb)
      Og[((size_t)(b * N_ + i)) * DI_ + h * DH_ + nb * 16 + lr] = f2bf(o[nb][r] * g);
  }
}

extern "C" void kernel_launch(void* const* d_in, const int* in_sizes, int n_in,
                              void* d_out, int out_size, void* d_ws, size_t ws_size,
                              hipStream_t stream) {
  const float* tokens = (const float*)d_in[0];
  const float* vres   = (const float*)d_in[1];
  const float* Wq     = (const float*)d_in[2];
  const float* Wkv    = (const float*)d_in[3];
  const float* Wo     = (const float*)d_in[4];
  const float* Wg     = (const float*)d_in[5];
  const float* Wmix   = (const float*)d_in[6];
  float* out = (float*)d_out;
  char* ws = (char*)d_ws;
  unsigned short* tokb = (unsigned short*)(ws);              // 8,388,608
  unsigned short* wcat = (unsigned short*)(ws + 8388608);    // 3,407,872
  unsigned short* wot  = (unsigned short*)(ws + 11796480);   // 1,048,576
  unsigned short* proj = (unsigned short*)(ws + 12845056);   // 13,631,488
  unsigned short* Qb   = (unsigned short*)(ws + 26476544);   // 4,194,304
  unsigned short* Kb   = (unsigned short*)(ws + 30670848);   // 4,194,304
  unsigned short* Vt   = (unsigned short*)(ws + 34865152);   // 4,194,304
  float*          gates= (float*)(ws + 39059456);            // 131,072
  unsigned short* Og   = (unsigned short*)(ws + 39190528);   // 4,194,304
  float2*         cs   = (float2*)(ws + 43384832);           // 524,288
  (void)in_sizes; (void)n_in; (void)out_size; (void)ws_size;

  k_prep<<<6464, 256, 0, stream>>>(tokens, Wq, Wkv, Wo, Wg, Wmix, tokb, wcat, wot, cs);

  dim3 g1(NCPAD / 128, (B_ * N_) / 128);
  k_gemm64<unsigned short><<<g1, 256, 0, stream>>>(tokb, wcat, proj, B_ * N_, NCPAD, DIM_);

  k_postv<<<(B_ * N_) / 8, 512, 0, stream>>>(proj, vres, cs, Qb, Kb, Vt, gates);

  k_attn4<<<512, 256, 0, stream>>>(Qb, Kb, Vt, gates, Og);

  dim3 g2(DIM_ / 128, (B_ * N_) / 128);
  k_gemm64<float><<<g2, 256, 0, stream>>>(Og, wot, out, B_ * N_, DIM_, DI_);
}

// Round 6
// 73.740 us; speedup vs baseline: 1.7019x; 1.0509x over previous
//
#include <hip/hip_runtime.h>

#define B_ 2
#define N_ 2048
#define DIM_ 1024
#define H_ 8
#define DH_ 64
#define DI_ 512
#define WIN_ 512
#define NCPAD 1664  // 13*128 padded proj cols: 512 q | 1024 kv | 8 g | 8 mix | 112 pad

typedef __bf16 bf16x8 __attribute__((ext_vector_type(8)));
typedef unsigned short ushortx8 __attribute__((ext_vector_type(8)));
typedef float floatx4 __attribute__((ext_vector_type(4)));

#define MFMA16(a, b, c) __builtin_amdgcn_mfma_f32_16x16x32_bf16((a), (b), (c), 0, 0, 0)

__device__ inline unsigned short f2bf(float f) {
  union { float f; unsigned u; } v; v.f = f;
  unsigned r = v.u + 0x7FFFu + ((v.u >> 16) & 1u);
  return (unsigned short)(r >> 16);
}
__device__ inline float bf2f(unsigned short u) {
  union { unsigned u; float f; } v; v.u = ((unsigned)u) << 16; return v.f;
}
__device__ inline float sigmoidf_(float x) { return 1.0f / (1.0f + __expf(-x)); }

__device__ __forceinline__ void gload_lds16(const unsigned short* g, unsigned short* l) {
  __builtin_amdgcn_global_load_lds(
      (const __attribute__((address_space(1))) void*)g,
      (__attribute__((address_space(3))) void*)l,
      16, 0, 0);
}

// ================= fused prep: trig table | tokens->bf16 | weight transposes =================
__global__ __launch_bounds__(256) void k_prep(const float* __restrict__ tokens,
                                              const float* __restrict__ Wq,
                                              const float* __restrict__ Wkv,
                                              const float* __restrict__ Wo,
                                              const float* __restrict__ Wg,
                                              const float* __restrict__ Wmix,
                                              unsigned short* __restrict__ tokb,
                                              unsigned short* __restrict__ wcat,
                                              unsigned short* __restrict__ wot,
                                              float2* __restrict__ cs) {
  __shared__ float t32[32][33];
  const int bid = blockIdx.x;
  const int tid = threadIdx.x;
  if (bid < 256) {
    int i = bid * 256 + tid;
    int n = i >> 5, t2 = i & 31;
    float inv = __expf(-(float)t2 * 0.2878231366242557f);  // ln(10000)/32
    float sv, cv;
    sincosf((float)n * inv, &sv, &cv);
    cs[i] = make_float2(cv, sv);
    return;
  }
  if (bid < 4352) {
    int i = (bid - 256) * 256 + tid;
    float4 v = reinterpret_cast<const float4*>(tokens)[i];
    ushort4 r;
    r.x = f2bf(v.x); r.y = f2bf(v.y); r.z = f2bf(v.z); r.w = f2bf(v.w);
    reinterpret_cast<ushort4*>(tokb)[i] = r;
    return;
  }
  if (bid >= 6400) {
    int idx = (bid - 6400) * 256 + tid;
    int j = idx >> 10;
    int c = idx & 1023;
    float v = (j < 8) ? Wg[c * 8 + j] : Wmix[c * 8 + (j - 8)];
    wcat[(size_t)(1536 + j) * 1024 + c] = f2bf(v);
    return;
  }
  const float* in;
  unsigned short* out;
  int Rin, Cin, c0, r0;
  if (bid < 4864) {
    int t = bid - 4352; in = Wq; out = wcat; Rin = 1024; Cin = 512;
    c0 = (t & 15) * 32; r0 = (t >> 4) * 32;
  } else if (bid < 5888) {
    int t = bid - 4864; in = Wkv; out = wcat + 512 * 1024; Rin = 1024; Cin = 1024;
    c0 = (t & 31) * 32; r0 = (t >> 5) * 32;
  } else {
    int t = bid - 5888; in = Wo; out = wot; Rin = 512; Cin = 1024;
    c0 = (t & 31) * 32; r0 = (t >> 5) * 32;
  }
  const int tx = tid & 31, ty = tid >> 5;
#pragma unroll
  for (int i = 0; i < 4; ++i)
    t32[ty + i * 8][tx] = in[(size_t)(r0 + ty + i * 8) * Cin + c0 + tx];
  __syncthreads();
#pragma unroll
  for (int i = 0; i < 4; ++i)
    out[(size_t)(c0 + ty + i * 8) * Rin + r0 + tx] = f2bf(t32[tx][ty + i * 8]);
}

// ================= BK=64 128x128 MFMA GEMM (proj): C bf16 = A * Bt^T =================
__global__ __launch_bounds__(256) void k_gemm64(const unsigned short* __restrict__ A,
                                                const unsigned short* __restrict__ Bt,
                                                unsigned short* __restrict__ C,
                                                int M, int Nc, int K) {
  __shared__ __align__(16) unsigned short As[128 * 64];
  __shared__ __align__(16) unsigned short Bs[128 * 64];
  const int tid = threadIdx.x;
  const int lane = tid & 63;
  const int wid = tid >> 6;
  const int m0 = blockIdx.y * 128;
  const int n0 = blockIdx.x * 128;
  const int wr = (wid >> 1) * 64;
  const int wc = (wid & 1) * 64;
  const int lr = lane & 15;
  const int lk = (lane >> 4) << 3;
  const int grow = tid >> 3;
  const int gcol = (tid & 7) << 3;
  const unsigned short* aP = A + (size_t)(m0 + grow) * K + gcol;
  const unsigned short* bP = Bt + (size_t)(n0 + grow) * K + gcol;
  unsigned short* lA = As + grow * 64 + gcol;
  unsigned short* lB = Bs + grow * 64 + gcol;
  floatx4 acc[4][4] = {};
  for (int k0 = 0; k0 < K; k0 += 64) {
    __syncthreads();
#pragma unroll
    for (int r = 0; r < 4; ++r) gload_lds16(aP + k0 + (size_t)(r * 32) * K, lA + r * 2048);
#pragma unroll
    for (int r = 0; r < 4; ++r) gload_lds16(bP + k0 + (size_t)(r * 32) * K, lB + r * 2048);
    __syncthreads();
#pragma unroll
    for (int kk = 0; kk < 2; ++kk) {
      bf16x8 af[4], bfr[4];
#pragma unroll
      for (int i = 0; i < 4; ++i)
        af[i] = *reinterpret_cast<const bf16x8*>(&As[(wr + i * 16 + lr) * 64 + kk * 32 + lk]);
#pragma unroll
      for (int j = 0; j < 4; ++j)
        bfr[j] = *reinterpret_cast<const bf16x8*>(&Bs[(wc + j * 16 + lr) * 64 + kk * 32 + lk]);
#pragma unroll
      for (int i = 0; i < 4; ++i)
#pragma unroll
        for (int j = 0; j < 4; ++j)
          acc[i][j] = MFMA16(af[i], bfr[j], acc[i][j]);
    }
  }
  const int r0 = (lane >> 4) << 2;
#pragma unroll
  for (int i = 0; i < 4; ++i)
#pragma unroll
    for (int j = 0; j < 4; ++j) {
      unsigned short* cp = C + (size_t)(m0 + wr + i * 16 + r0) * Nc + n0 + wc + j * 16 + lr;
#pragma unroll
      for (int r = 0; r < 4; ++r) cp[(size_t)r * Nc] = f2bf(acc[i][j][r]);
    }
}

// ================= BK=64 128x64 MFMA GEMM (out): 512 blocks -> 2 blocks/CU =================
__global__ __launch_bounds__(256) void k_gemmB(const unsigned short* __restrict__ A,
                                               const unsigned short* __restrict__ Bt,
                                               float* __restrict__ C,
                                               int M, int Nc, int K) {
  __shared__ __align__(16) unsigned short As[128 * 64];
  __shared__ __align__(16) unsigned short Bs[64 * 64];
  const int tid = threadIdx.x;
  const int lane = tid & 63;
  const int wid = tid >> 6;
  const int m0 = blockIdx.y * 128;
  const int n0 = blockIdx.x * 64;
  const int wr = (wid >> 1) * 64;
  const int wc = (wid & 1) * 32;
  const int lr = lane & 15;
  const int lk = (lane >> 4) << 3;
  const int grow = tid >> 3;        // 0..31
  const int gcol = (tid & 7) << 3;  // 0..56
  const unsigned short* aP = A + (size_t)(m0 + grow) * K + gcol;
  const unsigned short* bP = Bt + (size_t)(n0 + grow) * K + gcol;
  unsigned short* lA = As + grow * 64 + gcol;
  unsigned short* lB = Bs + grow * 64 + gcol;
  floatx4 acc[4][2] = {};
  for (int k0 = 0; k0 < K; k0 += 64) {
    __syncthreads();
#pragma unroll
    for (int r = 0; r < 4; ++r) gload_lds16(aP + k0 + (size_t)(r * 32) * K, lA + r * 2048);
#pragma unroll
    for (int r = 0; r < 2; ++r) gload_lds16(bP + k0 + (size_t)(r * 32) * K, lB + r * 2048);
    __syncthreads();
#pragma unroll
    for (int kk = 0; kk < 2; ++kk) {
      bf16x8 af[4], bfr[2];
#pragma unroll
      for (int i = 0; i < 4; ++i)
        af[i] = *reinterpret_cast<const bf16x8*>(&As[(wr + i * 16 + lr) * 64 + kk * 32 + lk]);
#pragma unroll
      for (int j = 0; j < 2; ++j)
        bfr[j] = *reinterpret_cast<const bf16x8*>(&Bs[(wc + j * 16 + lr) * 64 + kk * 32 + lk]);
#pragma unroll
      for (int i = 0; i < 4; ++i)
#pragma unroll
        for (int j = 0; j < 2; ++j)
          acc[i][j] = MFMA16(af[i], bfr[j], acc[i][j]);
    }
  }
  const int r0 = (lane >> 4) << 2;
#pragma unroll
  for (int i = 0; i < 4; ++i)
#pragma unroll
    for (int j = 0; j < 2; ++j) {
      float* cp = C + (size_t)(m0 + wr + i * 16 + r0) * Nc + n0 + wc + j * 16 + lr;
#pragma unroll
      for (int r = 0; r < 4; ++r) cp[(size_t)r * Nc] = acc[i][j][r];
    }
}

// ================= fused post: RoPE Q/K + gates + V lerp/tile =================
__global__ __launch_bounds__(512) void k_postv(const unsigned short* __restrict__ proj,
                                               const float* __restrict__ vres,
                                               const float2* __restrict__ cs,
                                               unsigned short* __restrict__ Qb,
                                               unsigned short* __restrict__ Kb,
                                               unsigned short* __restrict__ Vt,
                                               float* __restrict__ gates) {
  const int w = threadIdx.x >> 6, l = threadIdx.x & 63;
  const int row = blockIdx.x * 8 + w;
  const int b = row >> 11, n = row & (N_ - 1);
  const unsigned short* pr = proj + (size_t)row * NCPAD;
  if (l < H_) gates[(size_t)(b * H_ + l) * N_ + n] = sigmoidf_(bf2f(pr[1536 + l]));
  ushortx8 qv = *reinterpret_cast<const ushortx8*>(pr + 8 * l);
  ushortx8 kv = *reinterpret_cast<const ushortx8*>(pr + 512 + 8 * l);
  const int t2b = 4 * (l & 7);
  ushortx8 qo, ko;
#pragma unroll
  for (int p = 0; p < 4; ++p) {
    float2 c2 = cs[n * 32 + t2b + p];
    float q0 = bf2f(qv[2 * p]), q1 = bf2f(qv[2 * p + 1]);
    float k0 = bf2f(kv[2 * p]), k1 = bf2f(kv[2 * p + 1]);
    qo[2 * p]     = f2bf((q0 * c2.x - q1 * c2.y) * 0.125f);
    qo[2 * p + 1] = f2bf((q1 * c2.x + q0 * c2.y) * 0.125f);
    ko[2 * p]     = f2bf(k0 * c2.x - k1 * c2.y);
    ko[2 * p + 1] = f2bf(k1 * c2.x + k0 * c2.y);
  }
  const int h = l >> 3;
  const size_t off = ((size_t)(b * H_ + h) * N_ + n) * DH_ + 8 * (l & 7);
  *reinterpret_cast<ushortx8*>(Qb + off) = qo;
  *reinterpret_cast<ushortx8*>(Kb + off) = ko;
  const int hv = w;
  const int d = l;
  const int base_row = blockIdx.x * 8;
  const int bb = base_row >> 11;
  ushortx8 acc;
#pragma unroll
  for (int r = 0; r < 8; ++r) {
    const unsigned short* pr2 = proj + (size_t)(base_row + r) * NCPAD;
    const float mix = sigmoidf_(bf2f(pr2[1544 + hv]));
    const float pv = bf2f(pr2[1024 + hv * 64 + d]);
    const float vr = vres[((size_t)(bb * H_ + hv) * N_ + ((base_row + r) & (N_ - 1))) * DH_ + d];
    acc[r] = f2bf(pv + (vr - pv) * mix);
  }
  *reinterpret_cast<ushortx8*>(Vt + (size_t)(bb * H_ + hv) * N_ * DH_ +
                               (size_t)(blockIdx.x & 255) * 512 + d * 8) = acc;
}

// ================= 4-wave LDS-staged windowed attention =================
__global__ __launch_bounds__(256) void k_attn4(const unsigned short* __restrict__ Qb,
                                               const unsigned short* __restrict__ Kb,
                                               const unsigned short* __restrict__ Vt,
                                               const float* __restrict__ gates,
                                               unsigned short* __restrict__ Og) {
  __shared__ __align__(16) unsigned short Ks[2][64 * 64];
  __shared__ __align__(16) unsigned short Vs[2][64 * 64];
  __shared__ __align__(16) unsigned short Ps[4][16 * 72];
  const int bid = (int)blockIdx.x;
  const int xcd = bid & 7;
  const int seq = bid >> 3;           // 0..63 within XCD chunk
  const int bh = xcd * 2 + (seq >> 5);
  const int s = seq & 31;
  // long/short alternation: even s -> long q-tiles (31..16), odd s -> short (0..15)
  const int qt = (s & 1) ? (s >> 1) : (31 - (s >> 1));
  const int b = bh >> 3, h = bh & 7;
  const int qi0 = qt * 64;
  const int tid = threadIdx.x;
  const int w = tid >> 6;
  const int lane = tid & 63;
  const int lr = lane & 15;
  const int hi = lane >> 4;
  const int lk = hi << 3;
  const int qw0 = qi0 + w * 16;
  const unsigned short* Qh = Qb + (size_t)bh * N_ * DH_;
  const unsigned short* Kh = Kb + (size_t)bh * N_ * DH_;
  const unsigned short* Vh = Vt + (size_t)bh * N_ * DH_;
  bf16x8 aq0 = *reinterpret_cast<const bf16x8*>(Qh + (qw0 + lr) * DH_ + lk);
  bf16x8 aq1 = *reinterpret_cast<const bf16x8*>(Qh + (qw0 + lr) * DH_ + 32 + lk);
  floatx4 o[4] = {};
  float lsum[4] = {0.f, 0.f, 0.f, 0.f};

  const int s_row = tid >> 3;
  const int s_chk = tid & 7;

  auto stage = [&](int bufi, int j0) {
#pragma unroll
    for (int p = 0; p < 2; ++p) {
      const int row = s_row + p * 32;
      const int csw = s_chk ^ (row & 7);
      gload_lds16(Kh + (size_t)(j0 + row) * DH_ + csw * 8, &Ks[bufi][(row * 8 + s_chk) * 8]);
    }
#pragma unroll
    for (int p = 0; p < 2; ++p) {
      const int flat = p * 256 + tid;
      gload_lds16(Vh + (size_t)j0 * DH_ + flat * 8, &Vs[bufi][flat * 8]);
    }
  };

  auto compute = [&](int bufi, int j0, bool maskLo, bool maskHi) {
    floatx4 c[4];
    __builtin_amdgcn_s_setprio(1);
#pragma unroll
    for (int cc = 0; cc < 4; ++cc) {
      const int row = 16 * cc + lr;
      const int sw = row & 7;
      bf16x8 kf0 = *reinterpret_cast<const bf16x8*>(&Ks[bufi][row * 64 + ((hi ^ sw) << 3)]);
      bf16x8 kf1 = *reinterpret_cast<const bf16x8*>(&Ks[bufi][row * 64 + (((hi + 4) ^ sw) << 3)]);
      floatx4 a = {};
      a = MFMA16(aq0, kf0, a);
      a = MFMA16(aq1, kf1, a);
      c[cc] = a;
    }
    __builtin_amdgcn_s_setprio(0);
#pragma unroll
    for (int cc = 0; cc < 4; ++cc)
#pragma unroll
      for (int r = 0; r < 4; ++r) {
        const int i = qw0 + hi * 4 + r;
        const int j = j0 + 16 * cc + lr;
        float sc = c[cc][r];
        if (maskHi && j > i) sc = -1e30f;
        if (maskLo && (i - j) > WIN_) sc = -1e30f;
        const float p = __expf(sc);
        lsum[r] += p;
        Ps[w][(hi * 4 + r) * 72 + 16 * cc + lr] = f2bf(p);
      }
    bf16x8 pa0 = *reinterpret_cast<const bf16x8*>(&Ps[w][lr * 72 + lk]);
    bf16x8 pa1 = *reinterpret_cast<const bf16x8*>(&Ps[w][lr * 72 + 32 + lk]);
    __builtin_amdgcn_s_setprio(1);
#pragma unroll
    for (int nb = 0; nb < 4; ++nb) {
      bf16x8 v0 = *reinterpret_cast<const bf16x8*>(&Vs[bufi][lk * 64 + nb * 128 + lr * 8]);
      bf16x8 v1 = *reinterpret_cast<const bf16x8*>(&Vs[bufi][(32 + lk) * 64 + nb * 128 + lr * 8]);
      o[nb] = MFMA16(pa0, v0, o[nb]);
      o[nb] = MFMA16(pa1, v1, o[nb]);
    }
    __builtin_amdgcn_s_setprio(0);
  };

  const int jlo = (qi0 >= WIN_) ? (qi0 - WIN_) : 0;
  const int niter = (qi0 + 64 - jlo) >> 6;
  const bool needLo = (qi0 >= WIN_);

  stage(0, jlo);
  __syncthreads();
  int bufi = 0;
  for (int t = 0; t < niter; ++t) {
    const int j0 = jlo + t * 64;
    if (t + 1 < niter) stage(bufi ^ 1, j0 + 64);
    compute(bufi, j0, needLo && t == 0, t == niter - 1);
    __syncthreads();
    bufi ^= 1;
  }

#pragma unroll
  for (int r = 0; r < 4; ++r) {
    float ls = lsum[r];
#pragma unroll
    for (int off = 1; off < 16; off <<= 1) ls += __shfl_xor(ls, off, 16);
    const int i = qw0 + hi * 4 + r;
    const float g = gates[(size_t)bh * N_ + i] * __builtin_amdgcn_rcpf(ls);
#pragma unroll
    for (int nb = 0; nb < 4; ++nb)
      Og[((size_t)(b * N_ + i)) * DI_ + h * DH_ + nb * 16 + lr] = f2bf(o[nb][r] * g);
  }
}

extern "C" void kernel_launch(void* const* d_in, const int* in_sizes, int n_in,
                              void* d_out, int out_size, void* d_ws, size_t ws_size,
                              hipStream_t stream) {
  const float* tokens = (const float*)d_in[0];
  const float* vres   = (const float*)d_in[1];
  const float* Wq     = (const float*)d_in[2];
  const float* Wkv    = (const float*)d_in[3];
  const float* Wo     = (const float*)d_in[4];
  const float* Wg     = (const float*)d_in[5];
  const float* Wmix   = (const float*)d_in[6];
  float* out = (float*)d_out;
  char* ws = (char*)d_ws;
  unsigned short* tokb = (unsigned short*)(ws);              // 8,388,608
  unsigned short* wcat = (unsigned short*)(ws + 8388608);    // 3,407,872
  unsigned short* wot  = (unsigned short*)(ws + 11796480);   // 1,048,576
  unsigned short* proj = (unsigned short*)(ws + 12845056);   // 13,631,488
  unsigned short* Qb   = (unsigned short*)(ws + 26476544);   // 4,194,304
  unsigned short* Kb   = (unsigned short*)(ws + 30670848);   // 4,194,304
  unsigned short* Vt   = (unsigned short*)(ws + 34865152);   // 4,194,304
  float*          gates= (float*)(ws + 39059456);            // 131,072
  unsigned short* Og   = (unsigned short*)(ws + 39190528);   // 4,194,304
  float2*         cs   = (float2*)(ws + 43384832);           // 524,288
  (void)in_sizes; (void)n_in; (void)out_size; (void)ws_size;

  k_prep<<<6464, 256, 0, stream>>>(tokens, Wq, Wkv, Wo, Wg, Wmix, tokb, wcat, wot, cs);

  dim3 g1(NCPAD / 128, (B_ * N_) / 128);
  k_gemm64<<<g1, 256, 0, stream>>>(tokb, wcat, proj, B_ * N_, NCPAD, DIM_);

  k_postv<<<(B_ * N_) / 8, 512, 0, stream>>>(proj, vres, cs, Qb, Kb, Vt, gates);

  k_attn4<<<512, 256, 0, stream>>>(Qb, Kb, Vt, gates, Og);

  dim3 g2(DIM_ / 64, (B_ * N_) / 128);
  k_gemmB<<<g2, 256, 0, stream>>>(Og, wot, out, B_ * N_, DIM_, DI_);
}

// Round 7
// 66.181 us; speedup vs baseline: 1.8963x; 1.1142x over previous
//
#include <hip/hip_runtime.h>

#define B_ 2
#define N_ 2048
#define DIM_ 1024
#define H_ 8
#define DH_ 64
#define DI_ 512
#define WIN_ 512
#define NCPAD 1664  // 13*128 padded proj cols: 512 q | 1024 kv | 8 g | 8 mix | 112 pad

typedef __bf16 bf16x8 __attribute__((ext_vector_type(8)));
typedef unsigned short ushortx8 __attribute__((ext_vector_type(8)));
typedef float floatx4 __attribute__((ext_vector_type(4)));

#define MFMA16(a, b, c) __builtin_amdgcn_mfma_f32_16x16x32_bf16((a), (b), (c), 0, 0, 0)

__device__ inline unsigned short f2bf(float f) {
  union { float f; unsigned u; } v; v.f = f;
  unsigned r = v.u + 0x7FFFu + ((v.u >> 16) & 1u);
  return (unsigned short)(r >> 16);
}
__device__ inline float bf2f(unsigned short u) {
  union { unsigned u; float f; } v; v.u = ((unsigned)u) << 16; return v.f;
}
__device__ inline float sigmoidf_(float x) { return 1.0f / (1.0f + __expf(-x)); }

__device__ __forceinline__ void gload_lds16(const unsigned short* g, unsigned short* l) {
  __builtin_amdgcn_global_load_lds(
      (const __attribute__((address_space(1))) void*)g,
      (__attribute__((address_space(3))) void*)l,
      16, 0, 0);
}

// ================= fused prep: trig table | tokens->bf16 | weight transposes =================
__global__ __launch_bounds__(256) void k_prep(const float* __restrict__ tokens,
                                              const float* __restrict__ Wq,
                                              const float* __restrict__ Wkv,
                                              const float* __restrict__ Wo,
                                              const float* __restrict__ Wg,
                                              const float* __restrict__ Wmix,
                                              unsigned short* __restrict__ tokb,
                                              unsigned short* __restrict__ wcat,
                                              unsigned short* __restrict__ wot,
                                              float2* __restrict__ cs) {
  __shared__ float t32[32][33];
  const int bid = blockIdx.x;
  const int tid = threadIdx.x;
  if (bid < 256) {
    int i = bid * 256 + tid;
    int n = i >> 5, t2 = i & 31;
    float inv = __expf(-(float)t2 * 0.2878231366242557f);  // ln(10000)/32
    float sv, cv;
    sincosf((float)n * inv, &sv, &cv);
    cs[i] = make_float2(cv, sv);
    return;
  }
  if (bid < 4352) {
    int i = (bid - 256) * 256 + tid;
    float4 v = reinterpret_cast<const float4*>(tokens)[i];
    ushort4 r;
    r.x = f2bf(v.x); r.y = f2bf(v.y); r.z = f2bf(v.z); r.w = f2bf(v.w);
    reinterpret_cast<ushort4*>(tokb)[i] = r;
    return;
  }
  if (bid >= 6400) {
    int idx = (bid - 6400) * 256 + tid;
    int j = idx >> 10;
    int c = idx & 1023;
    float v = (j < 8) ? Wg[c * 8 + j] : Wmix[c * 8 + (j - 8)];
    wcat[(size_t)(1536 + j) * 1024 + c] = f2bf(v);
    return;
  }
  const float* in;
  unsigned short* out;
  int Rin, Cin, c0, r0;
  if (bid < 4864) {
    int t = bid - 4352; in = Wq; out = wcat; Rin = 1024; Cin = 512;
    c0 = (t & 15) * 32; r0 = (t >> 4) * 32;
  } else if (bid < 5888) {
    int t = bid - 4864; in = Wkv; out = wcat + 512 * 1024; Rin = 1024; Cin = 1024;
    c0 = (t & 31) * 32; r0 = (t >> 5) * 32;
  } else {
    int t = bid - 5888; in = Wo; out = wot; Rin = 512; Cin = 1024;
    c0 = (t & 31) * 32; r0 = (t >> 5) * 32;
  }
  const int tx = tid & 31, ty = tid >> 5;
#pragma unroll
  for (int i = 0; i < 4; ++i)
    t32[ty + i * 8][tx] = in[(size_t)(r0 + ty + i * 8) * Cin + c0 + tx];
  __syncthreads();
#pragma unroll
  for (int i = 0; i < 4; ++i)
    out[(size_t)(c0 + ty + i * 8) * Rin + r0 + tx] = f2bf(t32[tx][ty + i * 8]);
}

// ================= GEMM1: 128x128, BK=64, dbuf + stage-early + XOR-swizzled LDS =================
// C bf16 = A(bf16 [M][K]) * Bt(bf16 [Nc][K])^T
__global__ __launch_bounds__(256) void k_gemmP(const unsigned short* __restrict__ A,
                                               const unsigned short* __restrict__ Bt,
                                               unsigned short* __restrict__ C,
                                               int M, int Nc, int K) {
  __shared__ __align__(16) unsigned short As[2][128 * 64];
  __shared__ __align__(16) unsigned short Bs[2][128 * 64];
  const int tid = threadIdx.x;
  const int lane = tid & 63;
  const int wid = tid >> 6;
  const int m0 = blockIdx.y * 128;
  const int n0 = blockIdx.x * 128;
  const int wr = (wid >> 1) * 64;
  const int wc = (wid & 1) * 64;
  const int lr = lane & 15;
  const int hi = lane >> 4;
  const int grow = tid >> 3;        // 0..31 (row within 32-row staging round)
  const int gchk = tid & 7;         // 16B chunk within 128B row (linear LDS dest)
  const int csw = gchk ^ (grow & 7);  // pre-swizzled global source chunk
  const unsigned short* aP = A + (size_t)(m0 + grow) * K + csw * 8;
  const unsigned short* bP = Bt + (size_t)(n0 + grow) * K + csw * 8;
  const int ldst = grow * 64 + gchk * 8;
  const int off0 = ((hi ^ (lr & 7)) << 3);  // swizzled read chunk for kk=0 (shorts)
  floatx4 acc[4][4] = {};
  const int T = K >> 6;
#pragma unroll
  for (int r = 0; r < 4; ++r) {
    gload_lds16(aP + (size_t)(r * 32) * K, &As[0][ldst + r * 2048]);
    gload_lds16(bP + (size_t)(r * 32) * K, &Bs[0][ldst + r * 2048]);
  }
  __syncthreads();
  for (int t = 0; t < T; ++t) {
    const int cur = t & 1;
    if (t + 1 < T) {
      const int nxt = cur ^ 1;
      const int k1 = (t + 1) << 6;
#pragma unroll
      for (int r = 0; r < 4; ++r) {
        gload_lds16(aP + k1 + (size_t)(r * 32) * K, &As[nxt][ldst + r * 2048]);
        gload_lds16(bP + k1 + (size_t)(r * 32) * K, &Bs[nxt][ldst + r * 2048]);
      }
    }
#pragma unroll
    for (int kk = 0; kk < 2; ++kk) {
      const int off = off0 ^ (kk << 5);
      bf16x8 af[4], bfr[4];
#pragma unroll
      for (int i = 0; i < 4; ++i)
        af[i] = *reinterpret_cast<const bf16x8*>(&As[cur][(wr + i * 16 + lr) * 64 + off]);
#pragma unroll
      for (int j = 0; j < 4; ++j)
        bfr[j] = *reinterpret_cast<const bf16x8*>(&Bs[cur][(wc + j * 16 + lr) * 64 + off]);
#pragma unroll
      for (int i = 0; i < 4; ++i)
#pragma unroll
        for (int j = 0; j < 4; ++j)
          acc[i][j] = MFMA16(af[i], bfr[j], acc[i][j]);
    }
    __syncthreads();
  }
  const int r0 = hi << 2;
#pragma unroll
  for (int i = 0; i < 4; ++i)
#pragma unroll
    for (int j = 0; j < 4; ++j) {
      unsigned short* cp = C + (size_t)(m0 + wr + i * 16 + r0) * Nc + n0 + wc + j * 16 + lr;
#pragma unroll
      for (int r = 0; r < 4; ++r) cp[(size_t)r * Nc] = f2bf(acc[i][j][r]);
    }
}

// ================= GEMM2: 128x64, BK=64, dbuf + stage-early + XOR-swizzled LDS =================
__global__ __launch_bounds__(256) void k_gemmB(const unsigned short* __restrict__ A,
                                               const unsigned short* __restrict__ Bt,
                                               float* __restrict__ C,
                                               int M, int Nc, int K) {
  __shared__ __align__(16) unsigned short As[2][128 * 64];
  __shared__ __align__(16) unsigned short Bs[2][64 * 64];
  const int tid = threadIdx.x;
  const int lane = tid & 63;
  const int wid = tid >> 6;
  const int m0 = blockIdx.y * 128;
  const int n0 = blockIdx.x * 64;
  const int wr = (wid >> 1) * 64;
  const int wc = (wid & 1) * 32;
  const int lr = lane & 15;
  const int hi = lane >> 4;
  const int grow = tid >> 3;
  const int gchk = tid & 7;
  const int csw = gchk ^ (grow & 7);
  const unsigned short* aP = A + (size_t)(m0 + grow) * K + csw * 8;
  const unsigned short* bP = Bt + (size_t)(n0 + grow) * K + csw * 8;
  const int ldst = grow * 64 + gchk * 8;
  const int off0 = ((hi ^ (lr & 7)) << 3);
  floatx4 acc[4][2] = {};
  const int T = K >> 6;
#pragma unroll
  for (int r = 0; r < 4; ++r) gload_lds16(aP + (size_t)(r * 32) * K, &As[0][ldst + r * 2048]);
#pragma unroll
  for (int r = 0; r < 2; ++r) gload_lds16(bP + (size_t)(r * 32) * K, &Bs[0][ldst + r * 2048]);
  __syncthreads();
  for (int t = 0; t < T; ++t) {
    const int cur = t & 1;
    if (t + 1 < T) {
      const int nxt = cur ^ 1;
      const int k1 = (t + 1) << 6;
#pragma unroll
      for (int r = 0; r < 4; ++r) gload_lds16(aP + k1 + (size_t)(r * 32) * K, &As[nxt][ldst + r * 2048]);
#pragma unroll
      for (int r = 0; r < 2; ++r) gload_lds16(bP + k1 + (size_t)(r * 32) * K, &Bs[nxt][ldst + r * 2048]);
    }
#pragma unroll
    for (int kk = 0; kk < 2; ++kk) {
      const int off = off0 ^ (kk << 5);
      bf16x8 af[4], bfr[2];
#pragma unroll
      for (int i = 0; i < 4; ++i)
        af[i] = *reinterpret_cast<const bf16x8*>(&As[cur][(wr + i * 16 + lr) * 64 + off]);
#pragma unroll
      for (int j = 0; j < 2; ++j)
        bfr[j] = *reinterpret_cast<const bf16x8*>(&Bs[cur][(wc + j * 16 + lr) * 64 + off]);
#pragma unroll
      for (int i = 0; i < 4; ++i)
#pragma unroll
        for (int j = 0; j < 2; ++j)
          acc[i][j] = MFMA16(af[i], bfr[j], acc[i][j]);
    }
    __syncthreads();
  }
  const int r0 = hi << 2;
#pragma unroll
  for (int i = 0; i < 4; ++i)
#pragma unroll
    for (int j = 0; j < 2; ++j) {
      float* cp = C + (size_t)(m0 + wr + i * 16 + r0) * Nc + n0 + wc + j * 16 + lr;
#pragma unroll
      for (int r = 0; r < 4; ++r) cp[(size_t)r * Nc] = acc[i][j][r];
    }
}

// ================= fused post: RoPE Q/K + gates + V lerp/tile =================
__global__ __launch_bounds__(512) void k_postv(const unsigned short* __restrict__ proj,
                                               const float* __restrict__ vres,
                                               const float2* __restrict__ cs,
                                               unsigned short* __restrict__ Qb,
                                               unsigned short* __restrict__ Kb,
                                               unsigned short* __restrict__ Vt,
                                               float* __restrict__ gates) {
  const int w = threadIdx.x >> 6, l = threadIdx.x & 63;
  const int row = blockIdx.x * 8 + w;
  const int b = row >> 11, n = row & (N_ - 1);
  const unsigned short* pr = proj + (size_t)row * NCPAD;
  if (l < H_) gates[(size_t)(b * H_ + l) * N_ + n] = sigmoidf_(bf2f(pr[1536 + l]));
  ushortx8 qv = *reinterpret_cast<const ushortx8*>(pr + 8 * l);
  ushortx8 kv = *reinterpret_cast<const ushortx8*>(pr + 512 + 8 * l);
  const int t2b = 4 * (l & 7);
  ushortx8 qo, ko;
#pragma unroll
  for (int p = 0; p < 4; ++p) {
    float2 c2 = cs[n * 32 + t2b + p];
    float q0 = bf2f(qv[2 * p]), q1 = bf2f(qv[2 * p + 1]);
    float k0 = bf2f(kv[2 * p]), k1 = bf2f(kv[2 * p + 1]);
    qo[2 * p]     = f2bf((q0 * c2.x - q1 * c2.y) * 0.125f);
    qo[2 * p + 1] = f2bf((q1 * c2.x + q0 * c2.y) * 0.125f);
    ko[2 * p]     = f2bf(k0 * c2.x - k1 * c2.y);
    ko[2 * p + 1] = f2bf(k1 * c2.x + k0 * c2.y);
  }
  const int h = l >> 3;
  const size_t off = ((size_t)(b * H_ + h) * N_ + n) * DH_ + 8 * (l & 7);
  *reinterpret_cast<ushortx8*>(Qb + off) = qo;
  *reinterpret_cast<ushortx8*>(Kb + off) = ko;
  const int hv = w;
  const int d = l;
  const int base_row = blockIdx.x * 8;
  const int bb = base_row >> 11;
  ushortx8 acc;
#pragma unroll
  for (int r = 0; r < 8; ++r) {
    const unsigned short* pr2 = proj + (size_t)(base_row + r) * NCPAD;
    const float mix = sigmoidf_(bf2f(pr2[1544 + hv]));
    const float pv = bf2f(pr2[1024 + hv * 64 + d]);
    const float vr = vres[((size_t)(bb * H_ + hv) * N_ + ((base_row + r) & (N_ - 1))) * DH_ + d];
    acc[r] = f2bf(pv + (vr - pv) * mix);
  }
  *reinterpret_cast<ushortx8*>(Vt + (size_t)(bb * H_ + hv) * N_ * DH_ +
                               (size_t)(blockIdx.x & 255) * 512 + d * 8) = acc;
}

// ================= 4-wave LDS-staged windowed attention =================
__global__ __launch_bounds__(256) void k_attn4(const unsigned short* __restrict__ Qb,
                                               const unsigned short* __restrict__ Kb,
                                               const unsigned short* __restrict__ Vt,
                                               const float* __restrict__ gates,
                                               unsigned short* __restrict__ Og) {
  __shared__ __align__(16) unsigned short Ks[2][64 * 64];
  __shared__ __align__(16) unsigned short Vs[2][64 * 64];
  __shared__ __align__(16) unsigned short Ps[4][16 * 72];
  const int bid = (int)blockIdx.x;
  const int xcd = bid & 7;
  const int seq = bid >> 3;           // 0..63 within XCD chunk
  const int bh = xcd * 2 + (seq >> 5);
  const int s = seq & 31;
  const int qt = (s & 1) ? (s >> 1) : (31 - (s >> 1));
  const int b = bh >> 3, h = bh & 7;
  const int qi0 = qt * 64;
  const int tid = threadIdx.x;
  const int w = tid >> 6;
  const int lane = tid & 63;
  const int lr = lane & 15;
  const int hi = lane >> 4;
  const int lk = hi << 3;
  const int qw0 = qi0 + w * 16;
  const unsigned short* Qh = Qb + (size_t)bh * N_ * DH_;
  const unsigned short* Kh = Kb + (size_t)bh * N_ * DH_;
  const unsigned short* Vh = Vt + (size_t)bh * N_ * DH_;
  bf16x8 aq0 = *reinterpret_cast<const bf16x8*>(Qh + (qw0 + lr) * DH_ + lk);
  bf16x8 aq1 = *reinterpret_cast<const bf16x8*>(Qh + (qw0 + lr) * DH_ + 32 + lk);
  floatx4 o[4] = {};
  float lsum[4] = {0.f, 0.f, 0.f, 0.f};

  const int s_row = tid >> 3;
  const int s_chk = tid & 7;

  auto stage = [&](int bufi, int j0) {
#pragma unroll
    for (int p = 0; p < 2; ++p) {
      const int row = s_row + p * 32;
      const int csw = s_chk ^ (row & 7);
      gload_lds16(Kh + (size_t)(j0 + row) * DH_ + csw * 8, &Ks[bufi][(row * 8 + s_chk) * 8]);
    }
#pragma unroll
    for (int p = 0; p < 2; ++p) {
      const int flat = p * 256 + tid;
      gload_lds16(Vh + (size_t)j0 * DH_ + flat * 8, &Vs[bufi][flat * 8]);
    }
  };

  auto compute = [&](int bufi, int j0, bool maskLo, bool maskHi) {
    floatx4 c[4];
    __builtin_amdgcn_s_setprio(1);
#pragma unroll
    for (int cc = 0; cc < 4; ++cc) {
      const int row = 16 * cc + lr;
      const int sw = row & 7;
      bf16x8 kf0 = *reinterpret_cast<const bf16x8*>(&Ks[bufi][row * 64 + ((hi ^ sw) << 3)]);
      bf16x8 kf1 = *reinterpret_cast<const bf16x8*>(&Ks[bufi][row * 64 + (((hi + 4) ^ sw) << 3)]);
      floatx4 a = {};
      a = MFMA16(aq0, kf0, a);
      a = MFMA16(aq1, kf1, a);
      c[cc] = a;
    }
    __builtin_amdgcn_s_setprio(0);
#pragma unroll
    for (int cc = 0; cc < 4; ++cc)
#pragma unroll
      for (int r = 0; r < 4; ++r) {
        const int i = qw0 + hi * 4 + r;
        const int j = j0 + 16 * cc + lr;
        float sc = c[cc][r];
        if (maskHi && j > i) sc = -1e30f;
        if (maskLo && (i - j) > WIN_) sc = -1e30f;
        const float p = __expf(sc);
        lsum[r] += p;
        Ps[w][(hi * 4 + r) * 72 + 16 * cc + lr] = f2bf(p);
      }
    bf16x8 pa0 = *reinterpret_cast<const bf16x8*>(&Ps[w][lr * 72 + lk]);
    bf16x8 pa1 = *reinterpret_cast<const bf16x8*>(&Ps[w][lr * 72 + 32 + lk]);
    __builtin_amdgcn_s_setprio(1);
#pragma unroll
    for (int nb = 0; nb < 4; ++nb) {
      bf16x8 v0 = *reinterpret_cast<const bf16x8*>(&Vs[bufi][lk * 64 + nb * 128 + lr * 8]);
      bf16x8 v1 = *reinterpret_cast<const bf16x8*>(&Vs[bufi][(32 + lk) * 64 + nb * 128 + lr * 8]);
      o[nb] = MFMA16(pa0, v0, o[nb]);
      o[nb] = MFMA16(pa1, v1, o[nb]);
    }
    __builtin_amdgcn_s_setprio(0);
  };

  const int jlo = (qi0 >= WIN_) ? (qi0 - WIN_) : 0;
  const int niter = (qi0 + 64 - jlo) >> 6;
  const bool needLo = (qi0 >= WIN_);

  stage(0, jlo);
  __syncthreads();
  int bufi = 0;
  for (int t = 0; t < niter; ++t) {
    const int j0 = jlo + t * 64;
    if (t + 1 < niter) stage(bufi ^ 1, j0 + 64);
    compute(bufi, j0, needLo && t == 0, t == niter - 1);
    __syncthreads();
    bufi ^= 1;
  }

#pragma unroll
  for (int r = 0; r < 4; ++r) {
    float ls = lsum[r];
#pragma unroll
    for (int off = 1; off < 16; off <<= 1) ls += __shfl_xor(ls, off, 16);
    const int i = qw0 + hi * 4 + r;
    const float g = gates[(size_t)bh * N_ + i] * __builtin_amdgcn_rcpf(ls);
#pragma unroll
    for (int nb = 0; nb < 4; ++nb)
      Og[((size_t)(b * N_ + i)) * DI_ + h * DH_ + nb * 16 + lr] = f2bf(o[nb][r] * g);
  }
}

extern "C" void kernel_launch(void* const* d_in, const int* in_sizes, int n_in,
                              void* d_out, int out_size, void* d_ws, size_t ws_size,
                              hipStream_t stream) {
  const float* tokens = (const float*)d_in[0];
  const float* vres   = (const float*)d_in[1];
  const float* Wq     = (const float*)d_in[2];
  const float* Wkv    = (const float*)d_in[3];
  const float* Wo     = (const float*)d_in[4];
  const float* Wg     = (const float*)d_in[5];
  const float* Wmix   = (const float*)d_in[6];
  float* out = (float*)d_out;
  char* ws = (char*)d_ws;
  unsigned short* tokb = (unsigned short*)(ws);              // 8,388,608
  unsigned short* wcat = (unsigned short*)(ws + 8388608);    // 3,407,872
  unsigned short* wot  = (unsigned short*)(ws + 11796480);   // 1,048,576
  unsigned short* proj = (unsigned short*)(ws + 12845056);   // 13,631,488
  unsigned short* Qb   = (unsigned short*)(ws + 26476544);   // 4,194,304
  unsigned short* Kb   = (unsigned short*)(ws + 30670848);   // 4,194,304
  unsigned short* Vt   = (unsigned short*)(ws + 34865152);   // 4,194,304
  float*          gates= (float*)(ws + 39059456);            // 131,072
  unsigned short* Og   = (unsigned short*)(ws + 39190528);   // 4,194,304
  float2*         cs   = (float2*)(ws + 43384832);           // 524,288
  (void)in_sizes; (void)n_in; (void)out_size; (void)ws_size;

  k_prep<<<6464, 256, 0, stream>>>(tokens, Wq, Wkv, Wo, Wg, Wmix, tokb, wcat, wot, cs);

  dim3 g1(NCPAD / 128, (B_ * N_) / 128);
  k_gemmP<<<g1, 256, 0, stream>>>(tokb, wcat, proj, B_ * N_, NCPAD, DIM_);

  k_postv<<<(B_ * N_) / 8, 512, 0, stream>>>(proj, vres, cs, Qb, Kb, Vt, gates);

  k_attn4<<<512, 256, 0, stream>>>(Qb, Kb, Vt, gates, Og);

  dim3 g2(DIM_ / 64, (B_ * N_) / 128);
  k_gemmB<<<g2, 256, 0, stream>>>(Og, wot, out, B_ * N_, DIM_, DI_);
}